// Round 1
// baseline (975.859 us; speedup 1.0000x reference)
//
#include <hip/hip_runtime.h>

constexpr int D_   = 256;
constexpr int H_   = 8;
constexpr int DH   = 32;
constexpr int L_   = 4;
constexpr int P_   = 4;
constexpr int DFF_ = 1024;
constexpr int B_   = 4;
constexpr int NQ_  = 900;
constexpr int NV_  = 21260;
constexpr int MQ   = B_ * NQ_;   // 3600
constexpr int MV   = B_ * NV_;   // 85040

// ---------------------------------------------------------------------------
// Generic tiled f32 GEMM: C[M,N] = A[M,K] @ W[N,K]^T + bias[N]  (opt. ReLU)
// BM=BN=64, BK=16, 256 threads, 4x4 per thread.
// ---------------------------------------------------------------------------
template <bool RELU>
__global__ __launch_bounds__(256) void gemm64(const float* __restrict__ A,
                                              const float* __restrict__ W,
                                              const float* __restrict__ bias,
                                              float* __restrict__ C,
                                              int M, int N, int K) {
  constexpr int BK = 16;
  __shared__ float As[BK][68];
  __shared__ float Bs[BK][68];
  const int t  = threadIdx.x;
  const int n0 = blockIdx.x * 64;
  const int m0 = blockIdx.y * 64;
  const int lm = t >> 2;          // 0..63
  const int lk = (t & 3) * 4;     // 0,4,8,12
  const int tx = t & 15, ty = t >> 4;

  float acc[4][4] = {};

  for (int k0 = 0; k0 < K; k0 += BK) {
    float4 av;
    const int am = m0 + lm;
    if (am < M)
      av = *reinterpret_cast<const float4*>(&A[am * K + k0 + lk]);
    else
      av = make_float4(0.f, 0.f, 0.f, 0.f);
    As[lk + 0][lm] = av.x; As[lk + 1][lm] = av.y;
    As[lk + 2][lm] = av.z; As[lk + 3][lm] = av.w;

    const float4 bv =
        *reinterpret_cast<const float4*>(&W[(n0 + lm) * K + k0 + lk]);
    Bs[lk + 0][lm] = bv.x; Bs[lk + 1][lm] = bv.y;
    Bs[lk + 2][lm] = bv.z; Bs[lk + 3][lm] = bv.w;
    __syncthreads();

#pragma unroll
    for (int kk = 0; kk < BK; ++kk) {
      float a_[4], b_[4];
#pragma unroll
      for (int j = 0; j < 4; ++j) a_[j] = As[kk][ty * 4 + j];
#pragma unroll
      for (int i = 0; i < 4; ++i) b_[i] = Bs[kk][tx * 4 + i];
#pragma unroll
      for (int j = 0; j < 4; ++j)
#pragma unroll
        for (int i = 0; i < 4; ++i) acc[j][i] += a_[j] * b_[i];
    }
    __syncthreads();
  }

#pragma unroll
  for (int j = 0; j < 4; ++j) {
    const int m = m0 + ty * 4 + j;
    if (m >= M) break;
#pragma unroll
    for (int i = 0; i < 4; ++i) {
      const int n = n0 + tx * 4 + i;
      float v = acc[j][i] + bias[n];
      if (RELU) v = fmaxf(v, 0.f);
      C[m * N + n] = v;
    }
  }
}

// ---------------------------------------------------------------------------
// c = a + b (elementwise)
// ---------------------------------------------------------------------------
__global__ void add2(const float* __restrict__ a, const float* __restrict__ b,
                     float* __restrict__ c, int n) {
  const int i = blockIdx.x * blockDim.x + threadIdx.x;
  if (i < n) c[i] = a[i] + b[i];
}

// ---------------------------------------------------------------------------
// Deformable sampling. One block (256 thr) per (b,q). tid = h*32 + d.
// ---------------------------------------------------------------------------
__global__ __launch_bounds__(256) void deform(const float* __restrict__ refp,
                                              const float* __restrict__ off,
                                              const float* __restrict__ logits,
                                              const float* __restrict__ v,
                                              float* __restrict__ acc) {
  __shared__ float aw[H_ * L_ * P_];  // 128
  const int bq = blockIdx.x;   // b*NQ + qi
  const int b  = bq / NQ_;
  const int t  = threadIdx.x;
  const int h  = t >> 5, d = t & 31;

  if (t < 128) aw[t] = logits[bq * 128 + t];
  __syncthreads();
  if (t < 8) {
    float mx = -1e30f;
#pragma unroll
    for (int i = 0; i < 16; ++i) mx = fmaxf(mx, aw[t * 16 + i]);
    float e[16], s = 0.f;
#pragma unroll
    for (int i = 0; i < 16; ++i) { e[i] = expf(aw[t * 16 + i] - mx); s += e[i]; }
    const float inv = 1.f / s;
#pragma unroll
    for (int i = 0; i < 16; ++i) aw[t * 16 + i] = e[i] * inv;
  }
  __syncthreads();

  constexpr int ST[4] = {0, 16000, 20000, 21000};
  constexpr int HL[4] = {100, 50, 25, 13};
  constexpr int WL[4] = {160, 80, 40, 20};

  float a = 0.f;
#pragma unroll
  for (int l = 0; l < L_; ++l) {
    const float rx = refp[(bq * L_ + l) * 2 + 0];
    const float ry = refp[(bq * L_ + l) * 2 + 1];
    const float Wf = (float)WL[l], Hf = (float)HL[l];
    const int   Wi = WL[l], Hi = HL[l];
    const int vbase = (b * NV_ + ST[l]) * D_ + h * DH + d;
#pragma unroll
    for (int p = 0; p < P_; ++p) {
      const float ox = off[bq * D_ + h * 32 + l * 8 + p * 2 + 0];
      const float oy = off[bq * D_ + h * 32 + l * 8 + p * 2 + 1];
      const float locx = rx + ox / Wf;
      const float locy = ry + oy / Hf;
      const float xl = locx * Wf - 0.5f;
      const float yl = locy * Hf - 0.5f;
      const float x0 = floorf(xl), y0 = floorf(yl);
      const float wx = xl - x0, wy = yl - y0;
      const int x0i = (int)x0, y0i = (int)y0;
      const float w = aw[h * 16 + l * 4 + p];

      float s = 0.f;
#pragma unroll
      for (int c = 0; c < 4; ++c) {
        const int xi = x0i + (c & 1);
        const int yi = y0i + (c >> 1);
        const float cw = ((c & 1) ? wx : 1.f - wx) * ((c >> 1) ? wy : 1.f - wy);
        const bool valid = (xi >= 0) && (xi < Wi) && (yi >= 0) && (yi < Hi);
        const int xc = min(max(xi, 0), Wi - 1);
        const int yc = min(max(yi, 0), Hi - 1);
        const float g = v[vbase + (yc * Wi + xc) * D_];
        s += valid ? g * cw : 0.f;
      }
      a += w * s;
    }
  }
  acc[bq * D_ + t] = a;
}

// ---------------------------------------------------------------------------
// MHA, one block (256 thr) per (b,h,q) row. Streaming softmax over 900 keys.
// qhkh layout: [b*NQ+q][512]  (qh cols 0..255, kh cols 256..511)
// ---------------------------------------------------------------------------
__global__ __launch_bounds__(256) void mha(const float* __restrict__ qhkh,
                                           const float* __restrict__ vh,
                                           float* __restrict__ o) {
  __shared__ float sq[DH];
  __shared__ float sc[NQ_];
  __shared__ float red[256];
  __shared__ float pv[8][DH];
  const int bx = blockIdx.x;
  const int qi = bx % NQ_;
  const int h  = (bx / NQ_) % H_;
  const int b  = bx / (NQ_ * H_);
  const int t  = threadIdx.x;

  if (t < DH) sq[t] = qhkh[(b * NQ_ + qi) * 512 + h * DH + t];
  __syncthreads();

  const float scale = 0.17677669529663687f;  // 1/sqrt(32)
  float lmax = -1e30f;
  for (int k = t; k < NQ_; k += 256) {
    const float* kr = &qhkh[(b * NQ_ + k) * 512 + 256 + h * DH];
    float dp = 0.f;
#pragma unroll
    for (int dd = 0; dd < DH; ++dd) dp += sq[dd] * kr[dd];
    dp *= scale;
    sc[k] = dp;
    lmax = fmaxf(lmax, dp);
  }
  red[t] = lmax;
  __syncthreads();
  for (int s = 128; s > 0; s >>= 1) {
    if (t < s) red[t] = fmaxf(red[t], red[t + s]);
    __syncthreads();
  }
  const float mx = red[0];
  __syncthreads();

  float lsum = 0.f;
  for (int k = t; k < NQ_; k += 256) {
    const float e = expf(sc[k] - mx);
    sc[k] = e;
    lsum += e;
  }
  red[t] = lsum;
  __syncthreads();
  for (int s = 128; s > 0; s >>= 1) {
    if (t < s) red[t] += red[t + s];
    __syncthreads();
  }
  const float inv = 1.f / red[0];
  __syncthreads();

  const int g = t >> 5, dd = t & 31;
  float part = 0.f;
  for (int k = g; k < NQ_; k += 8)
    part += sc[k] * vh[(b * NQ_ + k) * D_ + h * DH + dd];
  pv[g][dd] = part;
  __syncthreads();
  if (t < DH) {
    float s = 0.f;
#pragma unroll
    for (int gg = 0; gg < 8; ++gg) s += pv[gg][t];
    o[(b * NQ_ + qi) * D_ + h * DH + t] = s * inv;
  }
}

// ---------------------------------------------------------------------------
// out = LayerNorm(res + add) * g + b ; one block per row, 256 threads.
// ---------------------------------------------------------------------------
__global__ __launch_bounds__(256) void ln(const float* __restrict__ res,
                                          const float* __restrict__ add,
                                          const float* __restrict__ g,
                                          const float* __restrict__ bt,
                                          float* __restrict__ out) {
  __shared__ float red[256];
  const int r = blockIdx.x, t = threadIdx.x;
  const float x = res[r * D_ + t] + add[r * D_ + t];
  red[t] = x;
  __syncthreads();
  for (int s = 128; s > 0; s >>= 1) {
    if (t < s) red[t] += red[t + s];
    __syncthreads();
  }
  const float mean = red[0] * (1.f / D_);
  __syncthreads();
  const float dx = x - mean;
  red[t] = dx * dx;
  __syncthreads();
  for (int s = 128; s > 0; s >>= 1) {
    if (t < s) red[t] += red[t + s];
    __syncthreads();
  }
  const float var = red[0] * (1.f / D_);
  out[r * D_ + t] = dx * rsqrtf(var + 1e-5f) * g[t] + bt[t];
}

// ---------------------------------------------------------------------------
extern "C" void kernel_launch(void* const* d_in, const int* in_sizes, int n_in,
                              void* d_out, int out_size, void* d_ws,
                              size_t ws_size, hipStream_t stream) {
  const float* tgt   = (const float*)d_in[0];
  const float* pos   = (const float*)d_in[1];
  const float* refp  = (const float*)d_in[2];
  const float* mem   = (const float*)d_in[3];
  const float* Wv    = (const float*)d_in[4];
  const float* bv    = (const float*)d_in[5];
  const float* Wo    = (const float*)d_in[6];
  const float* bo    = (const float*)d_in[7];
  const float* Wa    = (const float*)d_in[8];
  const float* ba    = (const float*)d_in[9];
  const float* Wca   = (const float*)d_in[10];
  const float* bca   = (const float*)d_in[11];
  const float* g1    = (const float*)d_in[12];
  const float* b1    = (const float*)d_in[13];
  const float* Win   = (const float*)d_in[14];
  const float* bin   = (const float*)d_in[15];
  const float* Wsa   = (const float*)d_in[16];
  const float* bsa   = (const float*)d_in[17];
  const float* g2    = (const float*)d_in[18];
  const float* b2    = (const float*)d_in[19];
  const float* W1    = (const float*)d_in[20];
  const float* bb1   = (const float*)d_in[21];
  const float* W2    = (const float*)d_in[22];
  const float* bb2   = (const float*)d_in[23];
  const float* g3    = (const float*)d_in[24];
  const float* b3    = (const float*)d_in[25];

  float* ws = (float*)d_ws;
  float* v      = ws;              ws += MV * D_;        // 21,770,240
  float* q      = ws;              ws += MQ * D_;
  float* off    = ws;              ws += MQ * D_;
  float* logits = ws;              ws += MQ * 128;
  float* accb   = ws;              ws += MQ * D_;
  float* tmp    = ws;              ws += MQ * D_;
  float* x1     = ws;              ws += MQ * D_;
  float* qk     = ws;              ws += MQ * D_;
  float* qhkh   = ws;              ws += MQ * 512;
  float* vh     = ws;              ws += MQ * D_;
  float* obuf   = ws;              ws += MQ * D_;
  float* x2     = ws;              ws += MQ * D_;
  float* h1     = ws;              ws += MQ * DFF_;

  const int mq_blk = (MQ + 63) / 64;   // 57
  const int mv_blk = (MV + 63) / 64;   // 1329

  // value projection: v = mem @ Wv^T + bv
  gemm64<false><<<dim3(D_ / 64, mv_blk), 256, 0, stream>>>(mem, Wv, bv, v,
                                                           MV, D_, D_);
  // q = tgt + pos
  add2<<<(MQ * D_ + 255) / 256, 256, 0, stream>>>(tgt, pos, q, MQ * D_);
  // sampling offsets + attention logits
  gemm64<false><<<dim3(D_ / 64, mq_blk), 256, 0, stream>>>(q, Wo, bo, off,
                                                           MQ, D_, D_);
  gemm64<false><<<dim3(128 / 64, mq_blk), 256, 0, stream>>>(q, Wa, ba, logits,
                                                            MQ, 128, D_);
  // deformable sampling
  deform<<<MQ, 256, 0, stream>>>(refp, off, logits, v, accb);
  // ca_out projection, then LN1(tgt + .)
  gemm64<false><<<dim3(D_ / 64, mq_blk), 256, 0, stream>>>(accb, Wca, bca, tmp,
                                                           MQ, D_, D_);
  ln<<<MQ, 256, 0, stream>>>(tgt, tmp, g1, b1, x1);
  // self-attention
  add2<<<(MQ * D_ + 255) / 256, 256, 0, stream>>>(x1, pos, qk, MQ * D_);
  gemm64<false><<<dim3(512 / 64, mq_blk), 256, 0, stream>>>(qk, Win, bin, qhkh,
                                                            MQ, 512, D_);
  gemm64<false><<<dim3(D_ / 64, mq_blk), 256, 0, stream>>>(
      x1, Win + 512 * D_, bin + 512, vh, MQ, D_, D_);
  mha<<<B_ * H_ * NQ_, 256, 0, stream>>>(qhkh, vh, obuf);
  gemm64<false><<<dim3(D_ / 64, mq_blk), 256, 0, stream>>>(obuf, Wsa, bsa, tmp,
                                                           MQ, D_, D_);
  ln<<<MQ, 256, 0, stream>>>(x1, tmp, g2, b2, x2);
  // FFN
  gemm64<true><<<dim3(DFF_ / 64, mq_blk), 256, 0, stream>>>(x2, W1, bb1, h1,
                                                            MQ, DFF_, D_);
  gemm64<false><<<dim3(D_ / 64, mq_blk), 256, 0, stream>>>(h1, W2, bb2, tmp,
                                                           MQ, D_, DFF_);
  ln<<<MQ, 256, 0, stream>>>(x2, tmp, g3, b3, (float*)d_out);
}

// Round 2
// 510.861 us; speedup vs baseline: 1.9102x; 1.9102x over previous
//
#include <hip/hip_runtime.h>

constexpr int D_   = 256;
constexpr int H_   = 8;
constexpr int DH   = 32;
constexpr int L_   = 4;
constexpr int P_   = 4;
constexpr int DFF_ = 1024;
constexpr int B_   = 4;
constexpr int NQ_  = 900;
constexpr int NV_  = 21260;
constexpr int MQ   = B_ * NQ_;   // 3600
constexpr int MV   = B_ * NV_;   // 85040

// ---------------------------------------------------------------------------
// Generic tiled f32 GEMM: C[M,N] = A[M,K] @ W[N,K]^T + bias[N]  (opt. ReLU)
// BM=BN=64, BK=16, 256 threads, 4x4 per thread.
// ---------------------------------------------------------------------------
template <bool RELU>
__global__ __launch_bounds__(256) void gemm64(const float* __restrict__ A,
                                              const float* __restrict__ W,
                                              const float* __restrict__ bias,
                                              float* __restrict__ C,
                                              int M, int N, int K) {
  constexpr int BK = 16;
  __shared__ float As[BK][68];
  __shared__ float Bs[BK][68];
  const int t  = threadIdx.x;
  const int n0 = blockIdx.x * 64;
  const int m0 = blockIdx.y * 64;
  const int lm = t >> 2;          // 0..63
  const int lk = (t & 3) * 4;     // 0,4,8,12
  const int tx = t & 15, ty = t >> 4;

  float acc[4][4] = {};

  for (int k0 = 0; k0 < K; k0 += BK) {
    float4 av;
    const int am = m0 + lm;
    if (am < M)
      av = *reinterpret_cast<const float4*>(&A[am * K + k0 + lk]);
    else
      av = make_float4(0.f, 0.f, 0.f, 0.f);
    As[lk + 0][lm] = av.x; As[lk + 1][lm] = av.y;
    As[lk + 2][lm] = av.z; As[lk + 3][lm] = av.w;

    const float4 bv =
        *reinterpret_cast<const float4*>(&W[(n0 + lm) * K + k0 + lk]);
    Bs[lk + 0][lm] = bv.x; Bs[lk + 1][lm] = bv.y;
    Bs[lk + 2][lm] = bv.z; Bs[lk + 3][lm] = bv.w;
    __syncthreads();

#pragma unroll
    for (int kk = 0; kk < BK; ++kk) {
      float a_[4], b_[4];
#pragma unroll
      for (int j = 0; j < 4; ++j) a_[j] = As[kk][ty * 4 + j];
#pragma unroll
      for (int i = 0; i < 4; ++i) b_[i] = Bs[kk][tx * 4 + i];
#pragma unroll
      for (int j = 0; j < 4; ++j)
#pragma unroll
        for (int i = 0; i < 4; ++i) acc[j][i] += a_[j] * b_[i];
    }
    __syncthreads();
  }

#pragma unroll
  for (int j = 0; j < 4; ++j) {
    const int m = m0 + ty * 4 + j;
    if (m >= M) break;
#pragma unroll
    for (int i = 0; i < 4; ++i) {
      const int n = n0 + tx * 4 + i;
      float v = acc[j][i] + bias[n];
      if (RELU) v = fmaxf(v, 0.f);
      C[m * N + n] = v;
    }
  }
}

// ---------------------------------------------------------------------------
// c = a + b (elementwise)
// ---------------------------------------------------------------------------
__global__ void add2(const float* __restrict__ a, const float* __restrict__ b,
                     float* __restrict__ c, int n) {
  const int i = blockIdx.x * blockDim.x + threadIdx.x;
  if (i < n) c[i] = a[i] + b[i];
}

// ---------------------------------------------------------------------------
// Deformable sampling. One block (256 thr) per (b,q). tid = h*32 + d.
// ---------------------------------------------------------------------------
__global__ __launch_bounds__(256) void deform(const float* __restrict__ refp,
                                              const float* __restrict__ off,
                                              const float* __restrict__ logits,
                                              const float* __restrict__ v,
                                              float* __restrict__ acc) {
  __shared__ float aw[H_ * L_ * P_];  // 128
  const int bq = blockIdx.x;   // b*NQ + qi
  const int b  = bq / NQ_;
  const int t  = threadIdx.x;
  const int h  = t >> 5, d = t & 31;

  if (t < 128) aw[t] = logits[bq * 128 + t];
  __syncthreads();
  if (t < 8) {
    float mx = -1e30f;
#pragma unroll
    for (int i = 0; i < 16; ++i) mx = fmaxf(mx, aw[t * 16 + i]);
    float e[16], s = 0.f;
#pragma unroll
    for (int i = 0; i < 16; ++i) { e[i] = expf(aw[t * 16 + i] - mx); s += e[i]; }
    const float inv = 1.f / s;
#pragma unroll
    for (int i = 0; i < 16; ++i) aw[t * 16 + i] = e[i] * inv;
  }
  __syncthreads();

  constexpr int ST[4] = {0, 16000, 20000, 21000};
  constexpr int HL[4] = {100, 50, 25, 13};
  constexpr int WL[4] = {160, 80, 40, 20};

  float a = 0.f;
#pragma unroll
  for (int l = 0; l < L_; ++l) {
    const float rx = refp[(bq * L_ + l) * 2 + 0];
    const float ry = refp[(bq * L_ + l) * 2 + 1];
    const float Wf = (float)WL[l], Hf = (float)HL[l];
    const int   Wi = WL[l], Hi = HL[l];
    const int vbase = (b * NV_ + ST[l]) * D_ + h * DH + d;
#pragma unroll
    for (int p = 0; p < P_; ++p) {
      const float ox = off[bq * D_ + h * 32 + l * 8 + p * 2 + 0];
      const float oy = off[bq * D_ + h * 32 + l * 8 + p * 2 + 1];
      const float locx = rx + ox / Wf;
      const float locy = ry + oy / Hf;
      const float xl = locx * Wf - 0.5f;
      const float yl = locy * Hf - 0.5f;
      const float x0 = floorf(xl), y0 = floorf(yl);
      const float wx = xl - x0, wy = yl - y0;
      const int x0i = (int)x0, y0i = (int)y0;
      const float w = aw[h * 16 + l * 4 + p];

      float s = 0.f;
#pragma unroll
      for (int c = 0; c < 4; ++c) {
        const int xi = x0i + (c & 1);
        const int yi = y0i + (c >> 1);
        const float cw = ((c & 1) ? wx : 1.f - wx) * ((c >> 1) ? wy : 1.f - wy);
        const bool valid = (xi >= 0) && (xi < Wi) && (yi >= 0) && (yi < Hi);
        const int xc = min(max(xi, 0), Wi - 1);
        const int yc = min(max(yi, 0), Hi - 1);
        const float g = v[vbase + (yc * Wi + xc) * D_];
        s += valid ? g * cw : 0.f;
      }
      a += w * s;
    }
  }
  acc[bq * D_ + t] = a;
}

// ---------------------------------------------------------------------------
// Flash MHA. One block per (b, h, q-tile). TQ=60 (15 exact tiles of NQ=900),
// key tiles TK=64 (15 tiles, last has 4 valid keys).
// Thread t: row r = t>>2 (0..63, valid r<60), lane group cg = t&3.
//   - S phase: 16 score cols [cg*16, cg*16+16), Q row in registers.
//   - PV phase: 8 output cols [cg*8, cg*8+8).
// Online softmax; row stats via __shfl_xor over the 4-lane group.
// ---------------------------------------------------------------------------
constexpr int TQ  = 60;
constexpr int TK  = 64;
constexpr int NQT = 15;   // 900 / 60

__global__ __launch_bounds__(256) void mha_flash(const float* __restrict__ qhkh,
                                                 const float* __restrict__ vh,
                                                 float* __restrict__ o) {
  __shared__ float Qs[TQ][33];     // 7920 B
  __shared__ float Kst[32][68];    // 8704 B  (transposed K tile)
  __shared__ float Vs[TK][36];     // 9216 B
  __shared__ float Ps[TQ + 4][68]; // 17408 B (rows >= TQ unused)

  const int bx = blockIdx.x;
  const int qt = bx % NQT;
  const int h  = (bx / NQT) % H_;
  const int b  = bx / (NQT * H_);
  const int t  = threadIdx.x;
  const int q0 = qt * TQ;

  // stage Q tile
  for (int e = t; e < TQ * 32; e += 256) {
    const int d = e & 31, r = e >> 5;
    Qs[r][d] = qhkh[(size_t)(b * NQ_ + q0 + r) * 512 + h * DH + d];
  }
  __syncthreads();

  const int r  = t >> 2;
  const int cg = t & 3;
  const int ct0 = cg * 16;   // score col base
  const int oc0 = cg * 8;    // output col base
  const bool act = (r < TQ);

  float qreg[32];
  if (act) {
#pragma unroll
    for (int d = 0; d < 32; ++d) qreg[d] = Qs[r][d];
  }

  float O_[8] = {};
  float m = -1e30f, l = 0.f;
  const float scale = 0.17677669529663687f;  // 1/sqrt(32)

  for (int kt = 0; kt < 15; ++kt) {
    const int k0 = kt * TK;
    const int nk = min(TK, NQ_ - k0);
    __syncthreads();  // protect Kst/Vs from previous iteration's readers
    // stage K (transposed) and V
    for (int e = t; e < TK * 32; e += 256) {
      const int d = e & 31, k = e >> 5;
      float kv = 0.f, vv = 0.f;
      if (k < nk) {
        kv = qhkh[(size_t)(b * NQ_ + k0 + k) * 512 + 256 + h * DH + d];
        vv = vh[(size_t)(b * NQ_ + k0 + k) * D_ + h * DH + d];
      }
      Kst[d][k] = kv;
      Vs[k][d]  = vv;
    }
    __syncthreads();

    if (act) {
      // scores for 16 cols
      float s[16];
#pragma unroll
      for (int i = 0; i < 16; ++i) s[i] = 0.f;
#pragma unroll
      for (int d = 0; d < 32; ++d) {
        const float qv = qreg[d];
#pragma unroll
        for (int ii = 0; ii < 4; ++ii) {
          const float4 kv = *reinterpret_cast<const float4*>(&Kst[d][ct0 + 4 * ii]);
          s[4 * ii + 0] += qv * kv.x;
          s[4 * ii + 1] += qv * kv.y;
          s[4 * ii + 2] += qv * kv.z;
          s[4 * ii + 3] += qv * kv.w;
        }
      }
      float tm = -1e30f;
#pragma unroll
      for (int i = 0; i < 16; ++i) {
        s[i] = (ct0 + i < nk) ? s[i] * scale : -1e30f;
        tm = fmaxf(tm, s[i]);
      }
      tm = fmaxf(tm, __shfl_xor(tm, 1));
      tm = fmaxf(tm, __shfl_xor(tm, 2));
      const float mn = fmaxf(m, tm);
      const float sc = __expf(m - mn);
      m = mn;
      float rs = 0.f;
      float p[16];
#pragma unroll
      for (int i = 0; i < 16; ++i) {
        p[i] = __expf(s[i] - mn);
        rs += p[i];
      }
      rs += __shfl_xor(rs, 1);
      rs += __shfl_xor(rs, 2);
      l = l * sc + rs;
#pragma unroll
      for (int j = 0; j < 8; ++j) O_[j] *= sc;
#pragma unroll
      for (int ii = 0; ii < 4; ++ii)
        *reinterpret_cast<float4*>(&Ps[r][ct0 + 4 * ii]) =
            make_float4(p[4 * ii], p[4 * ii + 1], p[4 * ii + 2], p[4 * ii + 3]);
    }
    __syncthreads();

    if (act) {
#pragma unroll 8
      for (int k = 0; k < TK; ++k) {
        const float pv = Ps[r][k];
        const float4 v0 = *reinterpret_cast<const float4*>(&Vs[k][oc0]);
        const float4 v1 = *reinterpret_cast<const float4*>(&Vs[k][oc0 + 4]);
        O_[0] += pv * v0.x; O_[1] += pv * v0.y;
        O_[2] += pv * v0.z; O_[3] += pv * v0.w;
        O_[4] += pv * v1.x; O_[5] += pv * v1.y;
        O_[6] += pv * v1.z; O_[7] += pv * v1.w;
      }
    }
  }

  if (act) {
    const float inv = 1.f / l;
    float* op = &o[(size_t)(b * NQ_ + q0 + r) * D_ + h * DH + oc0];
#pragma unroll
    for (int j = 0; j < 8; ++j) op[j] = O_[j] * inv;
  }
}

// ---------------------------------------------------------------------------
// out = LayerNorm(res + add) * g + b ; one block per row, 256 threads.
// ---------------------------------------------------------------------------
__global__ __launch_bounds__(256) void ln(const float* __restrict__ res,
                                          const float* __restrict__ add,
                                          const float* __restrict__ g,
                                          const float* __restrict__ bt,
                                          float* __restrict__ out) {
  __shared__ float red[256];
  const int r = blockIdx.x, t = threadIdx.x;
  const float x = res[r * D_ + t] + add[r * D_ + t];
  red[t] = x;
  __syncthreads();
  for (int s = 128; s > 0; s >>= 1) {
    if (t < s) red[t] += red[t + s];
    __syncthreads();
  }
  const float mean = red[0] * (1.f / D_);
  __syncthreads();
  const float dx = x - mean;
  red[t] = dx * dx;
  __syncthreads();
  for (int s = 128; s > 0; s >>= 1) {
    if (t < s) red[t] += red[t + s];
    __syncthreads();
  }
  const float var = red[0] * (1.f / D_);
  out[r * D_ + t] = dx * rsqrtf(var + 1e-5f) * g[t] + bt[t];
}

// ---------------------------------------------------------------------------
extern "C" void kernel_launch(void* const* d_in, const int* in_sizes, int n_in,
                              void* d_out, int out_size, void* d_ws,
                              size_t ws_size, hipStream_t stream) {
  const float* tgt   = (const float*)d_in[0];
  const float* pos   = (const float*)d_in[1];
  const float* refp  = (const float*)d_in[2];
  const float* mem   = (const float*)d_in[3];
  const float* Wv    = (const float*)d_in[4];
  const float* bv    = (const float*)d_in[5];
  const float* Wo    = (const float*)d_in[6];
  const float* bo    = (const float*)d_in[7];
  const float* Wa    = (const float*)d_in[8];
  const float* ba    = (const float*)d_in[9];
  const float* Wca   = (const float*)d_in[10];
  const float* bca   = (const float*)d_in[11];
  const float* g1    = (const float*)d_in[12];
  const float* b1    = (const float*)d_in[13];
  const float* Win   = (const float*)d_in[14];
  const float* bin   = (const float*)d_in[15];
  const float* Wsa   = (const float*)d_in[16];
  const float* bsa   = (const float*)d_in[17];
  const float* g2    = (const float*)d_in[18];
  const float* b2    = (const float*)d_in[19];
  const float* W1    = (const float*)d_in[20];
  const float* bb1   = (const float*)d_in[21];
  const float* W2    = (const float*)d_in[22];
  const float* bb2   = (const float*)d_in[23];
  const float* g3    = (const float*)d_in[24];
  const float* b3    = (const float*)d_in[25];

  float* ws = (float*)d_ws;
  float* v      = ws;              ws += MV * D_;
  float* q      = ws;              ws += MQ * D_;
  float* off    = ws;              ws += MQ * D_;
  float* logits = ws;              ws += MQ * 128;
  float* accb   = ws;              ws += MQ * D_;
  float* tmp    = ws;              ws += MQ * D_;
  float* x1     = ws;              ws += MQ * D_;
  float* qk     = ws;              ws += MQ * D_;
  float* qhkh   = ws;              ws += MQ * 512;
  float* vh     = ws;              ws += MQ * D_;
  float* obuf   = ws;              ws += MQ * D_;
  float* x2     = ws;              ws += MQ * D_;
  float* h1     = ws;              ws += MQ * DFF_;

  const int mq_blk = (MQ + 63) / 64;   // 57
  const int mv_blk = (MV + 63) / 64;   // 1329

  // value projection: v = mem @ Wv^T + bv
  gemm64<false><<<dim3(D_ / 64, mv_blk), 256, 0, stream>>>(mem, Wv, bv, v,
                                                           MV, D_, D_);
  // q = tgt + pos
  add2<<<(MQ * D_ + 255) / 256, 256, 0, stream>>>(tgt, pos, q, MQ * D_);
  // sampling offsets + attention logits
  gemm64<false><<<dim3(D_ / 64, mq_blk), 256, 0, stream>>>(q, Wo, bo, off,
                                                           MQ, D_, D_);
  gemm64<false><<<dim3(128 / 64, mq_blk), 256, 0, stream>>>(q, Wa, ba, logits,
                                                            MQ, 128, D_);
  // deformable sampling
  deform<<<MQ, 256, 0, stream>>>(refp, off, logits, v, accb);
  // ca_out projection, then LN1(tgt + .)
  gemm64<false><<<dim3(D_ / 64, mq_blk), 256, 0, stream>>>(accb, Wca, bca, tmp,
                                                           MQ, D_, D_);
  ln<<<MQ, 256, 0, stream>>>(tgt, tmp, g1, b1, x1);
  // self-attention
  add2<<<(MQ * D_ + 255) / 256, 256, 0, stream>>>(x1, pos, qk, MQ * D_);
  gemm64<false><<<dim3(512 / 64, mq_blk), 256, 0, stream>>>(qk, Win, bin, qhkh,
                                                            MQ, 512, D_);
  gemm64<false><<<dim3(D_ / 64, mq_blk), 256, 0, stream>>>(
      x1, Win + 512 * D_, bin + 512, vh, MQ, D_, D_);
  mha_flash<<<B_ * H_ * NQT, 256, 0, stream>>>(qhkh, vh, obuf);
  gemm64<false><<<dim3(D_ / 64, mq_blk), 256, 0, stream>>>(obuf, Wsa, bsa, tmp,
                                                           MQ, D_, D_);
  ln<<<MQ, 256, 0, stream>>>(x1, tmp, g2, b2, x2);
  // FFN
  gemm64<true><<<dim3(DFF_ / 64, mq_blk), 256, 0, stream>>>(x2, W1, bb1, h1,
                                                            MQ, DFF_, D_);
  gemm64<false><<<dim3(D_ / 64, mq_blk), 256, 0, stream>>>(h1, W2, bb2, tmp,
                                                           MQ, D_, DFF_);
  ln<<<MQ, 256, 0, stream>>>(x2, tmp, g3, b3, (float*)d_out);
}

// Round 3
// 386.612 us; speedup vs baseline: 2.5241x; 1.3214x over previous
//
#include <hip/hip_runtime.h>

constexpr int D_   = 256;
constexpr int H_   = 8;
constexpr int DH   = 32;
constexpr int L_   = 4;
constexpr int P_   = 4;
constexpr int DFF_ = 1024;
constexpr int B_   = 4;
constexpr int NQ_  = 900;
constexpr int NV_  = 21260;
constexpr int MQ   = B_ * NQ_;   // 3600
constexpr int MV   = B_ * NV_;   // 85040

typedef __attribute__((ext_vector_type(8))) short short8;
typedef __attribute__((ext_vector_type(4))) float f32x4;

// f32 -> bf16 (round-to-nearest-even), as raw ushort
static __device__ __forceinline__ unsigned short f2bf(float x) {
  union { float f; unsigned int u; } v;
  v.f = x;
  const unsigned int r = v.u + 0x7fffu + ((v.u >> 16) & 1u);
  return (unsigned short)(r >> 16);
}

// ---------------------------------------------------------------------------
// Weight conversion: 8 segments f32 -> bf16, one launch.
// ---------------------------------------------------------------------------
struct CvtArgs {
  const float* src[8];
  unsigned short* dst[8];
  int n[8];
};

__global__ __launch_bounds__(256) void cvtw(CvtArgs a) {
  const int seg = blockIdx.y;
  const int n = a.n[seg];
  const float* __restrict__ s = a.src[seg];
  unsigned short* __restrict__ d = a.dst[seg];
  for (int i = (blockIdx.x * 256 + threadIdx.x) * 4; i < n;
       i += gridDim.x * 256 * 4) {
    const float4 v = *reinterpret_cast<const float4*>(&s[i]);
    d[i + 0] = f2bf(v.x); d[i + 1] = f2bf(v.y);
    d[i + 2] = f2bf(v.z); d[i + 3] = f2bf(v.w);
  }
}

// ---------------------------------------------------------------------------
// MFMA bf16 GEMM: C[M,N] = A[M,K](f32) @ Wbf[N,K]^T(bf16) + bias, opt ReLU.
// BM=BN=128, BK=32, 256 threads = 4 waves, wave tile 64x64 (4x4 frags of
// 16x16x32). A converted f32->bf16 during LDS staging. LDS rows padded to
// 40 bf16 (80 B): fragment ds_read_b128 across 16 lanes lands 2-way on
// banks (free, m136).
// ---------------------------------------------------------------------------
template <bool RELU>
__global__ __launch_bounds__(256) void gemm_mfma(
    const float* __restrict__ A, const unsigned short* __restrict__ Wbf,
    const float* __restrict__ bias, float* __restrict__ C,
    int M, int N, int K) {
  constexpr int BK = 32;
  constexpr int LDR = 40;  // padded row length (bf16 elems)
  __shared__ unsigned short As[128][LDR];
  __shared__ unsigned short Bs[128][LDR];

  const int t    = threadIdx.x;
  const int wave = t >> 6;
  const int l    = t & 63;
  const int n0   = blockIdx.x * 128;
  const int m0   = blockIdx.y * 128;
  const int wm   = (wave >> 1) * 64;
  const int wn   = (wave & 1) * 64;

  const int srow = t >> 1;        // 0..127 staging row
  const int sseg = (t & 1) * 16;  // k offset 0 or 16

  f32x4 acc[4][4];
#pragma unroll
  for (int i = 0; i < 4; ++i)
#pragma unroll
    for (int j = 0; j < 4; ++j) acc[i][j] = (f32x4)0.f;

  const int lr = l & 15;          // fragment row/col within 16
  const int lk = (l >> 4) * 8;    // fragment k base

  for (int k0 = 0; k0 < K; k0 += BK) {
    // --- stage A (f32 -> bf16) ---
    {
      const int am = m0 + srow;
      unsigned short u[16];
      if (am < M) {
#pragma unroll
        for (int j = 0; j < 4; ++j) {
          const float4 av =
              *reinterpret_cast<const float4*>(&A[(size_t)am * K + k0 + sseg + 4 * j]);
          u[4 * j + 0] = f2bf(av.x); u[4 * j + 1] = f2bf(av.y);
          u[4 * j + 2] = f2bf(av.z); u[4 * j + 3] = f2bf(av.w);
        }
      } else {
#pragma unroll
        for (int j = 0; j < 16; ++j) u[j] = 0;
      }
      *reinterpret_cast<short8*>(&As[srow][sseg])     = *reinterpret_cast<short8*>(&u[0]);
      *reinterpret_cast<short8*>(&As[srow][sseg + 8]) = *reinterpret_cast<short8*>(&u[8]);
    }
    // --- stage B (already bf16) ---
    {
      const short8 b0 =
          *reinterpret_cast<const short8*>(&Wbf[(size_t)(n0 + srow) * K + k0 + sseg]);
      const short8 b1 =
          *reinterpret_cast<const short8*>(&Wbf[(size_t)(n0 + srow) * K + k0 + sseg + 8]);
      *reinterpret_cast<short8*>(&Bs[srow][sseg])     = b0;
      *reinterpret_cast<short8*>(&Bs[srow][sseg + 8]) = b1;
    }
    __syncthreads();

    short8 af[4], bf[4];
#pragma unroll
    for (int fi = 0; fi < 4; ++fi)
      af[fi] = *reinterpret_cast<const short8*>(&As[wm + fi * 16 + lr][lk]);
#pragma unroll
    for (int fj = 0; fj < 4; ++fj)
      bf[fj] = *reinterpret_cast<const short8*>(&Bs[wn + fj * 16 + lr][lk]);

#pragma unroll
    for (int fi = 0; fi < 4; ++fi)
#pragma unroll
      for (int fj = 0; fj < 4; ++fj)
        acc[fi][fj] = __builtin_amdgcn_mfma_f32_16x16x32_bf16(
            af[fi], bf[fj], acc[fi][fj], 0, 0, 0);
    __syncthreads();
  }

  // epilogue: D row = (l>>4)*4 + i, col = l&15
  const int orow = (l >> 4) * 4;
#pragma unroll
  for (int fi = 0; fi < 4; ++fi) {
#pragma unroll
    for (int fj = 0; fj < 4; ++fj) {
      const int n = n0 + wn + fj * 16 + lr;
      const float bn = bias[n];
#pragma unroll
      for (int i = 0; i < 4; ++i) {
        const int m = m0 + wm + fi * 16 + orow + i;
        if (m < M) {
          float v = acc[fi][fj][i] + bn;
          if (RELU) v = fmaxf(v, 0.f);
          C[(size_t)m * N + n] = v;
        }
      }
    }
  }
}

// ---------------------------------------------------------------------------
// c = a + b (elementwise)
// ---------------------------------------------------------------------------
__global__ void add2(const float* __restrict__ a, const float* __restrict__ b,
                     float* __restrict__ c, int n) {
  const int i = blockIdx.x * blockDim.x + threadIdx.x;
  if (i < n) c[i] = a[i] + b[i];
}

// ---------------------------------------------------------------------------
// Deformable sampling. One block (256 thr) per (b,q). tid = h*32 + d.
// ---------------------------------------------------------------------------
__global__ __launch_bounds__(256) void deform(const float* __restrict__ refp,
                                              const float* __restrict__ off,
                                              const float* __restrict__ logits,
                                              const float* __restrict__ v,
                                              float* __restrict__ acc) {
  __shared__ float aw[H_ * L_ * P_];  // 128
  const int bq = blockIdx.x;
  const int b  = bq / NQ_;
  const int t  = threadIdx.x;
  const int h  = t >> 5, d = t & 31;

  if (t < 128) aw[t] = logits[bq * 128 + t];
  __syncthreads();
  if (t < 8) {
    float mx = -1e30f;
#pragma unroll
    for (int i = 0; i < 16; ++i) mx = fmaxf(mx, aw[t * 16 + i]);
    float e[16], s = 0.f;
#pragma unroll
    for (int i = 0; i < 16; ++i) { e[i] = expf(aw[t * 16 + i] - mx); s += e[i]; }
    const float inv = 1.f / s;
#pragma unroll
    for (int i = 0; i < 16; ++i) aw[t * 16 + i] = e[i] * inv;
  }
  __syncthreads();

  constexpr int ST[4] = {0, 16000, 20000, 21000};
  constexpr int HL[4] = {100, 50, 25, 13};
  constexpr int WL[4] = {160, 80, 40, 20};

  float a = 0.f;
#pragma unroll
  for (int l = 0; l < L_; ++l) {
    const float rx = refp[(bq * L_ + l) * 2 + 0];
    const float ry = refp[(bq * L_ + l) * 2 + 1];
    const float Wf = (float)WL[l], Hf = (float)HL[l];
    const int   Wi = WL[l], Hi = HL[l];
    const int vbase = (b * NV_ + ST[l]) * D_ + h * DH + d;
#pragma unroll
    for (int p = 0; p < P_; ++p) {
      const float ox = off[bq * D_ + h * 32 + l * 8 + p * 2 + 0];
      const float oy = off[bq * D_ + h * 32 + l * 8 + p * 2 + 1];
      const float locx = rx + ox / Wf;
      const float locy = ry + oy / Hf;
      const float xl = locx * Wf - 0.5f;
      const float yl = locy * Hf - 0.5f;
      const float x0 = floorf(xl), y0 = floorf(yl);
      const float wx = xl - x0, wy = yl - y0;
      const int x0i = (int)x0, y0i = (int)y0;
      const float w = aw[h * 16 + l * 4 + p];

      float s = 0.f;
#pragma unroll
      for (int c = 0; c < 4; ++c) {
        const int xi = x0i + (c & 1);
        const int yi = y0i + (c >> 1);
        const float cw = ((c & 1) ? wx : 1.f - wx) * ((c >> 1) ? wy : 1.f - wy);
        const bool valid = (xi >= 0) && (xi < Wi) && (yi >= 0) && (yi < Hi);
        const int xc = min(max(xi, 0), Wi - 1);
        const int yc = min(max(yi, 0), Hi - 1);
        const float g = v[vbase + (yc * Wi + xc) * D_];
        s += valid ? g * cw : 0.f;
      }
      a += w * s;
    }
  }
  acc[bq * D_ + t] = a;
}

// ---------------------------------------------------------------------------
// Flash MHA (unchanged from round 2).
// ---------------------------------------------------------------------------
constexpr int TQ  = 60;
constexpr int TK  = 64;
constexpr int NQT = 15;

__global__ __launch_bounds__(256) void mha_flash(const float* __restrict__ qhkh,
                                                 const float* __restrict__ vh,
                                                 float* __restrict__ o) {
  __shared__ float Qs[TQ][33];
  __shared__ float Kst[32][68];
  __shared__ float Vs[TK][36];
  __shared__ float Ps[TQ + 4][68];

  const int bx = blockIdx.x;
  const int qt = bx % NQT;
  const int h  = (bx / NQT) % H_;
  const int b  = bx / (NQT * H_);
  const int t  = threadIdx.x;
  const int q0 = qt * TQ;

  for (int e = t; e < TQ * 32; e += 256) {
    const int d = e & 31, r = e >> 5;
    Qs[r][d] = qhkh[(size_t)(b * NQ_ + q0 + r) * 512 + h * DH + d];
  }
  __syncthreads();

  const int r  = t >> 2;
  const int cg = t & 3;
  const int ct0 = cg * 16;
  const int oc0 = cg * 8;
  const bool act = (r < TQ);

  float qreg[32];
  if (act) {
#pragma unroll
    for (int d = 0; d < 32; ++d) qreg[d] = Qs[r][d];
  }

  float O_[8] = {};
  float m = -1e30f, l = 0.f;
  const float scale = 0.17677669529663687f;

  for (int kt = 0; kt < 15; ++kt) {
    const int k0 = kt * TK;
    const int nk = min(TK, NQ_ - k0);
    __syncthreads();
    for (int e = t; e < TK * 32; e += 256) {
      const int d = e & 31, k = e >> 5;
      float kv = 0.f, vv = 0.f;
      if (k < nk) {
        kv = qhkh[(size_t)(b * NQ_ + k0 + k) * 512 + 256 + h * DH + d];
        vv = vh[(size_t)(b * NQ_ + k0 + k) * D_ + h * DH + d];
      }
      Kst[d][k] = kv;
      Vs[k][d]  = vv;
    }
    __syncthreads();

    if (act) {
      float s[16];
#pragma unroll
      for (int i = 0; i < 16; ++i) s[i] = 0.f;
#pragma unroll
      for (int d = 0; d < 32; ++d) {
        const float qv = qreg[d];
#pragma unroll
        for (int ii = 0; ii < 4; ++ii) {
          const float4 kv = *reinterpret_cast<const float4*>(&Kst[d][ct0 + 4 * ii]);
          s[4 * ii + 0] += qv * kv.x;
          s[4 * ii + 1] += qv * kv.y;
          s[4 * ii + 2] += qv * kv.z;
          s[4 * ii + 3] += qv * kv.w;
        }
      }
      float tm = -1e30f;
#pragma unroll
      for (int i = 0; i < 16; ++i) {
        s[i] = (ct0 + i < nk) ? s[i] * scale : -1e30f;
        tm = fmaxf(tm, s[i]);
      }
      tm = fmaxf(tm, __shfl_xor(tm, 1));
      tm = fmaxf(tm, __shfl_xor(tm, 2));
      const float mn = fmaxf(m, tm);
      const float sc = __expf(m - mn);
      m = mn;
      float rs = 0.f;
      float p[16];
#pragma unroll
      for (int i = 0; i < 16; ++i) {
        p[i] = __expf(s[i] - mn);
        rs += p[i];
      }
      rs += __shfl_xor(rs, 1);
      rs += __shfl_xor(rs, 2);
      l = l * sc + rs;
#pragma unroll
      for (int j = 0; j < 8; ++j) O_[j] *= sc;
#pragma unroll
      for (int ii = 0; ii < 4; ++ii)
        *reinterpret_cast<float4*>(&Ps[r][ct0 + 4 * ii]) =
            make_float4(p[4 * ii], p[4 * ii + 1], p[4 * ii + 2], p[4 * ii + 3]);
    }
    __syncthreads();

    if (act) {
#pragma unroll 8
      for (int k = 0; k < TK; ++k) {
        const float pv = Ps[r][k];
        const float4 v0 = *reinterpret_cast<const float4*>(&Vs[k][oc0]);
        const float4 v1 = *reinterpret_cast<const float4*>(&Vs[k][oc0 + 4]);
        O_[0] += pv * v0.x; O_[1] += pv * v0.y;
        O_[2] += pv * v0.z; O_[3] += pv * v0.w;
        O_[4] += pv * v1.x; O_[5] += pv * v1.y;
        O_[6] += pv * v1.z; O_[7] += pv * v1.w;
      }
    }
  }

  if (act) {
    const float inv = 1.f / l;
    float* op = &o[(size_t)(b * NQ_ + q0 + r) * D_ + h * DH + oc0];
#pragma unroll
    for (int j = 0; j < 8; ++j) op[j] = O_[j] * inv;
  }
}

// ---------------------------------------------------------------------------
// out = LayerNorm(res + add) * g + b
// ---------------------------------------------------------------------------
__global__ __launch_bounds__(256) void ln(const float* __restrict__ res,
                                          const float* __restrict__ add,
                                          const float* __restrict__ g,
                                          const float* __restrict__ bt,
                                          float* __restrict__ out) {
  __shared__ float red[256];
  const int r = blockIdx.x, t = threadIdx.x;
  const float x = res[r * D_ + t] + add[r * D_ + t];
  red[t] = x;
  __syncthreads();
  for (int s = 128; s > 0; s >>= 1) {
    if (t < s) red[t] += red[t + s];
    __syncthreads();
  }
  const float mean = red[0] * (1.f / D_);
  __syncthreads();
  const float dx = x - mean;
  red[t] = dx * dx;
  __syncthreads();
  for (int s = 128; s > 0; s >>= 1) {
    if (t < s) red[t] += red[t + s];
    __syncthreads();
  }
  const float var = red[0] * (1.f / D_);
  out[r * D_ + t] = dx * rsqrtf(var + 1e-5f) * g[t] + bt[t];
}

// ---------------------------------------------------------------------------
extern "C" void kernel_launch(void* const* d_in, const int* in_sizes, int n_in,
                              void* d_out, int out_size, void* d_ws,
                              size_t ws_size, hipStream_t stream) {
  const float* tgt   = (const float*)d_in[0];
  const float* pos   = (const float*)d_in[1];
  const float* refp  = (const float*)d_in[2];
  const float* mem   = (const float*)d_in[3];
  const float* Wv    = (const float*)d_in[4];
  const float* bv    = (const float*)d_in[5];
  const float* Wo    = (const float*)d_in[6];
  const float* bo    = (const float*)d_in[7];
  const float* Wa    = (const float*)d_in[8];
  const float* ba    = (const float*)d_in[9];
  const float* Wca   = (const float*)d_in[10];
  const float* bca   = (const float*)d_in[11];
  const float* g1    = (const float*)d_in[12];
  const float* b1    = (const float*)d_in[13];
  const float* Win   = (const float*)d_in[14];
  const float* bin   = (const float*)d_in[15];
  const float* Wsa   = (const float*)d_in[16];
  const float* bsa   = (const float*)d_in[17];
  const float* g2    = (const float*)d_in[18];
  const float* b2    = (const float*)d_in[19];
  const float* W1    = (const float*)d_in[20];
  const float* bb1   = (const float*)d_in[21];
  const float* W2    = (const float*)d_in[22];
  const float* bb2   = (const float*)d_in[23];
  const float* g3    = (const float*)d_in[24];
  const float* b3    = (const float*)d_in[25];

  float* ws = (float*)d_ws;
  float* v      = ws;              ws += MV * D_;
  float* q      = ws;              ws += MQ * D_;
  float* off    = ws;              ws += MQ * D_;
  float* logits = ws;              ws += MQ * 128;
  float* accb   = ws;              ws += MQ * D_;
  float* tmp    = ws;              ws += MQ * D_;
  float* x1     = ws;              ws += MQ * D_;
  float* qk     = ws;              ws += MQ * D_;
  float* qhkh   = ws;              ws += MQ * 512;
  float* vh     = ws;              ws += MQ * D_;
  float* obuf   = ws;              ws += MQ * D_;
  float* x2     = ws;              ws += MQ * D_;
  float* h1     = ws;              ws += MQ * DFF_;
  // bf16 weight buffers
  unsigned short* wb = (unsigned short*)ws;
  unsigned short* Wv_bf  = wb;  wb += 256 * 256;
  unsigned short* Wo_bf  = wb;  wb += 256 * 256;
  unsigned short* Wa_bf  = wb;  wb += 128 * 256;
  unsigned short* Wca_bf = wb;  wb += 256 * 256;
  unsigned short* Win_bf = wb;  wb += 768 * 256;
  unsigned short* Wsa_bf = wb;  wb += 256 * 256;
  unsigned short* W1_bf  = wb;  wb += 1024 * 256;
  unsigned short* W2_bf  = wb;  wb += 256 * 1024;

  // convert all weights to bf16 (one launch)
  CvtArgs ca;
  ca.src[0] = Wv;  ca.dst[0] = Wv_bf;  ca.n[0] = 256 * 256;
  ca.src[1] = Wo;  ca.dst[1] = Wo_bf;  ca.n[1] = 256 * 256;
  ca.src[2] = Wa;  ca.dst[2] = Wa_bf;  ca.n[2] = 128 * 256;
  ca.src[3] = Wca; ca.dst[3] = Wca_bf; ca.n[3] = 256 * 256;
  ca.src[4] = Win; ca.dst[4] = Win_bf; ca.n[4] = 768 * 256;
  ca.src[5] = Wsa; ca.dst[5] = Wsa_bf; ca.n[5] = 256 * 256;
  ca.src[6] = W1;  ca.dst[6] = W1_bf;  ca.n[6] = 1024 * 256;
  ca.src[7] = W2;  ca.dst[7] = W2_bf;  ca.n[7] = 256 * 1024;
  cvtw<<<dim3(64, 8), 256, 0, stream>>>(ca);

  const int mqb = (MQ + 127) / 128;   // 29
  const int mvb = (MV + 127) / 128;   // 665

  // value projection
  gemm_mfma<false><<<dim3(256 / 128, mvb), 256, 0, stream>>>(mem, Wv_bf, bv, v,
                                                             MV, 256, 256);
  // q = tgt + pos
  add2<<<(MQ * D_ + 255) / 256, 256, 0, stream>>>(tgt, pos, q, MQ * D_);
  // sampling offsets + attention logits
  gemm_mfma<false><<<dim3(256 / 128, mqb), 256, 0, stream>>>(q, Wo_bf, bo, off,
                                                             MQ, 256, 256);
  gemm_mfma<false><<<dim3(128 / 128, mqb), 256, 0, stream>>>(q, Wa_bf, ba,
                                                             logits, MQ, 128, 256);
  // deformable sampling
  deform<<<MQ, 256, 0, stream>>>(refp, off, logits, v, accb);
  // ca_out projection, then LN1(tgt + .)
  gemm_mfma<false><<<dim3(256 / 128, mqb), 256, 0, stream>>>(accb, Wca_bf, bca,
                                                             tmp, MQ, 256, 256);
  ln<<<MQ, 256, 0, stream>>>(tgt, tmp, g1, b1, x1);
  // self-attention
  add2<<<(MQ * D_ + 255) / 256, 256, 0, stream>>>(x1, pos, qk, MQ * D_);
  gemm_mfma<false><<<dim3(512 / 128, mqb), 256, 0, stream>>>(qk, Win_bf, bin,
                                                             qhkh, MQ, 512, 256);
  gemm_mfma<false><<<dim3(256 / 128, mqb), 256, 0, stream>>>(
      x1, Win_bf + 512 * 256, bin + 512, vh, MQ, 256, 256);
  mha_flash<<<B_ * H_ * NQT, 256, 0, stream>>>(qhkh, vh, obuf);
  gemm_mfma<false><<<dim3(256 / 128, mqb), 256, 0, stream>>>(obuf, Wsa_bf, bsa,
                                                             tmp, MQ, 256, 256);
  ln<<<MQ, 256, 0, stream>>>(x1, tmp, g2, b2, x2);
  // FFN
  gemm_mfma<true><<<dim3(1024 / 128, mqb), 256, 0, stream>>>(x2, W1_bf, bb1, h1,
                                                             MQ, 1024, 256);
  gemm_mfma<false><<<dim3(256 / 128, mqb), 256, 0, stream>>>(h1, W2_bf, bb2,
                                                             tmp, MQ, 256, 1024);
  ln<<<MQ, 256, 0, stream>>>(x2, tmp, g3, b3, (float*)d_out);
}

// Round 4
// 304.208 us; speedup vs baseline: 3.2079x; 1.2709x over previous
//
#include <hip/hip_runtime.h>

constexpr int D_   = 256;
constexpr int H_   = 8;
constexpr int DH   = 32;
constexpr int L_   = 4;
constexpr int P_   = 4;
constexpr int DFF_ = 1024;
constexpr int B_   = 4;
constexpr int NQ_  = 900;
constexpr int NV_  = 21260;
constexpr int MQ   = B_ * NQ_;   // 3600
constexpr int MV   = B_ * NV_;   // 85040

typedef __attribute__((ext_vector_type(8))) short short8;
typedef __attribute__((ext_vector_type(4))) float f32x4;

// f32 -> bf16 (round-to-nearest-even), as raw ushort
static __device__ __forceinline__ unsigned short f2bf(float x) {
  union { float f; unsigned int u; } v;
  v.f = x;
  const unsigned int r = v.u + 0x7fffu + ((v.u >> 16) & 1u);
  return (unsigned short)(r >> 16);
}

// ---------------------------------------------------------------------------
// Weight conversion: 8 segments f32 -> bf16, one launch.
// ---------------------------------------------------------------------------
struct CvtArgs {
  const float* src[8];
  unsigned short* dst[8];
  int n[8];
};

__global__ __launch_bounds__(256) void cvtw(CvtArgs a) {
  const int seg = blockIdx.y;
  const int n = a.n[seg];
  const float* __restrict__ s = a.src[seg];
  unsigned short* __restrict__ d = a.dst[seg];
  for (int i = (blockIdx.x * 256 + threadIdx.x) * 4; i < n;
       i += gridDim.x * 256 * 4) {
    const float4 v = *reinterpret_cast<const float4*>(&s[i]);
    d[i + 0] = f2bf(v.x); d[i + 1] = f2bf(v.y);
    d[i + 2] = f2bf(v.z); d[i + 3] = f2bf(v.w);
  }
}

// ---------------------------------------------------------------------------
// MFMA bf16 GEMM: C[M,N] = A[M,K](f32) @ Wbf[N,K]^T(bf16) + bias, opt ReLU.
// BM=BN=128, BK=32, 256 threads = 4 waves, wave tile 64x64.
// ---------------------------------------------------------------------------
template <bool RELU>
__global__ __launch_bounds__(256) void gemm_mfma(
    const float* __restrict__ A, const unsigned short* __restrict__ Wbf,
    const float* __restrict__ bias, float* __restrict__ C,
    int M, int N, int K) {
  constexpr int BK = 32;
  constexpr int LDR = 40;
  __shared__ unsigned short As[128][LDR];
  __shared__ unsigned short Bs[128][LDR];

  const int t    = threadIdx.x;
  const int wave = t >> 6;
  const int l    = t & 63;
  const int n0   = blockIdx.x * 128;
  const int m0   = blockIdx.y * 128;
  const int wm   = (wave >> 1) * 64;
  const int wn   = (wave & 1) * 64;

  const int srow = t >> 1;
  const int sseg = (t & 1) * 16;

  f32x4 acc[4][4];
#pragma unroll
  for (int i = 0; i < 4; ++i)
#pragma unroll
    for (int j = 0; j < 4; ++j) acc[i][j] = (f32x4)0.f;

  const int lr = l & 15;
  const int lk = (l >> 4) * 8;

  for (int k0 = 0; k0 < K; k0 += BK) {
    {
      const int am = m0 + srow;
      unsigned short u[16];
      if (am < M) {
#pragma unroll
        for (int j = 0; j < 4; ++j) {
          const float4 av =
              *reinterpret_cast<const float4*>(&A[(size_t)am * K + k0 + sseg + 4 * j]);
          u[4 * j + 0] = f2bf(av.x); u[4 * j + 1] = f2bf(av.y);
          u[4 * j + 2] = f2bf(av.z); u[4 * j + 3] = f2bf(av.w);
        }
      } else {
#pragma unroll
        for (int j = 0; j < 16; ++j) u[j] = 0;
      }
      *reinterpret_cast<short8*>(&As[srow][sseg])     = *reinterpret_cast<short8*>(&u[0]);
      *reinterpret_cast<short8*>(&As[srow][sseg + 8]) = *reinterpret_cast<short8*>(&u[8]);
    }
    {
      const short8 b0 =
          *reinterpret_cast<const short8*>(&Wbf[(size_t)(n0 + srow) * K + k0 + sseg]);
      const short8 b1 =
          *reinterpret_cast<const short8*>(&Wbf[(size_t)(n0 + srow) * K + k0 + sseg + 8]);
      *reinterpret_cast<short8*>(&Bs[srow][sseg])     = b0;
      *reinterpret_cast<short8*>(&Bs[srow][sseg + 8]) = b1;
    }
    __syncthreads();

    short8 af[4], bf[4];
#pragma unroll
    for (int fi = 0; fi < 4; ++fi)
      af[fi] = *reinterpret_cast<const short8*>(&As[wm + fi * 16 + lr][lk]);
#pragma unroll
    for (int fj = 0; fj < 4; ++fj)
      bf[fj] = *reinterpret_cast<const short8*>(&Bs[wn + fj * 16 + lr][lk]);

#pragma unroll
    for (int fi = 0; fi < 4; ++fi)
#pragma unroll
      for (int fj = 0; fj < 4; ++fj)
        acc[fi][fj] = __builtin_amdgcn_mfma_f32_16x16x32_bf16(
            af[fi], bf[fj], acc[fi][fj], 0, 0, 0);
    __syncthreads();
  }

  const int orow = (l >> 4) * 4;
#pragma unroll
  for (int fi = 0; fi < 4; ++fi) {
#pragma unroll
    for (int fj = 0; fj < 4; ++fj) {
      const int n = n0 + wn + fj * 16 + lr;
      const float bn = bias[n];
#pragma unroll
      for (int i = 0; i < 4; ++i) {
        const int m = m0 + wm + fi * 16 + orow + i;
        if (m < M) {
          float v = acc[fi][fj][i] + bn;
          if (RELU) v = fmaxf(v, 0.f);
          C[(size_t)m * N + n] = v;
        }
      }
    }
  }
}

// ---------------------------------------------------------------------------
// c = a + b (elementwise)
// ---------------------------------------------------------------------------
__global__ void add2(const float* __restrict__ a, const float* __restrict__ b,
                     float* __restrict__ c, int n) {
  const int i = blockIdx.x * blockDim.x + threadIdx.x;
  if (i < n) c[i] = a[i] + b[i];
}

// ---------------------------------------------------------------------------
// Deformable sampling. One block (256 thr) per (b,q). tid = h*32 + d.
// ---------------------------------------------------------------------------
__global__ __launch_bounds__(256) void deform(const float* __restrict__ refp,
                                              const float* __restrict__ off,
                                              const float* __restrict__ logits,
                                              const float* __restrict__ v,
                                              float* __restrict__ acc) {
  __shared__ float aw[H_ * L_ * P_];
  const int bq = blockIdx.x;
  const int b  = bq / NQ_;
  const int t  = threadIdx.x;
  const int h  = t >> 5, d = t & 31;

  if (t < 128) aw[t] = logits[bq * 128 + t];
  __syncthreads();
  if (t < 8) {
    float mx = -1e30f;
#pragma unroll
    for (int i = 0; i < 16; ++i) mx = fmaxf(mx, aw[t * 16 + i]);
    float e[16], s = 0.f;
#pragma unroll
    for (int i = 0; i < 16; ++i) { e[i] = expf(aw[t * 16 + i] - mx); s += e[i]; }
    const float inv = 1.f / s;
#pragma unroll
    for (int i = 0; i < 16; ++i) aw[t * 16 + i] = e[i] * inv;
  }
  __syncthreads();

  constexpr int ST[4] = {0, 16000, 20000, 21000};
  constexpr int HL[4] = {100, 50, 25, 13};
  constexpr int WL[4] = {160, 80, 40, 20};

  float a = 0.f;
#pragma unroll
  for (int l = 0; l < L_; ++l) {
    const float rx = refp[(bq * L_ + l) * 2 + 0];
    const float ry = refp[(bq * L_ + l) * 2 + 1];
    const float Wf = (float)WL[l], Hf = (float)HL[l];
    const int   Wi = WL[l], Hi = HL[l];
    const int vbase = (b * NV_ + ST[l]) * D_ + h * DH + d;
#pragma unroll
    for (int p = 0; p < P_; ++p) {
      const float ox = off[bq * D_ + h * 32 + l * 8 + p * 2 + 0];
      const float oy = off[bq * D_ + h * 32 + l * 8 + p * 2 + 1];
      const float locx = rx + ox / Wf;
      const float locy = ry + oy / Hf;
      const float xl = locx * Wf - 0.5f;
      const float yl = locy * Hf - 0.5f;
      const float x0 = floorf(xl), y0 = floorf(yl);
      const float wx = xl - x0, wy = yl - y0;
      const int x0i = (int)x0, y0i = (int)y0;
      const float w = aw[h * 16 + l * 4 + p];

      float s = 0.f;
#pragma unroll
      for (int c = 0; c < 4; ++c) {
        const int xi = x0i + (c & 1);
        const int yi = y0i + (c >> 1);
        const float cw = ((c & 1) ? wx : 1.f - wx) * ((c >> 1) ? wy : 1.f - wy);
        const bool valid = (xi >= 0) && (xi < Wi) && (yi >= 0) && (yi < Hi);
        const int xc = min(max(xi, 0), Wi - 1);
        const int yc = min(max(yi, 0), Hi - 1);
        const float g = v[vbase + (yc * Wi + xc) * D_];
        s += valid ? g * cw : 0.f;
      }
      a += w * s;
    }
  }
  acc[bq * D_ + t] = a;
}

// ---------------------------------------------------------------------------
// MFMA flash MHA. One block per (b, h, 64-q-tile); 4 waves x 16 q-rows.
// Fragment layouts as validated by gemm_mfma (rounds 2-3):
//   A: row = lane&15, k = (lane>>4)*8 + j
//   B: col = lane&15, k = (lane>>4)*8 + j
//   D: col = lane&15, row = (lane>>4)*4 + i
// Online softmax on D-layout: row stats in i-index, col-reduce over the
// 16-lane group via __shfl_xor 1/2/4/8. P staged to LDS bf16 (wave-private
// rows), PV via 4 MFMAs reading P as A-frags and V^T as B-frags.
// ---------------------------------------------------------------------------
constexpr int TQM  = 64;
constexpr int NQTM = (NQ_ + TQM - 1) / TQM;   // 15

__global__ __launch_bounds__(256) void mha_mfma(const float* __restrict__ qhkh,
                                                const float* __restrict__ vh,
                                                float* __restrict__ o) {
  __shared__ unsigned short Qs[64][40];    // 5120 B
  __shared__ unsigned short Ks[64][40];    // 5120 B
  __shared__ unsigned short Vts[32][72];   // 4608 B (transposed V tile)
  __shared__ unsigned short Ps[64][72];    // 9216 B

  const int bx = blockIdx.x;
  const int qt = bx % NQTM;
  const int h  = (bx / NQTM) % H_;
  const int b  = bx / (NQTM * H_);
  const int t  = threadIdx.x;
  const int wave = t >> 6;
  const int l    = t & 63;
  const int q0   = qt * TQM;
  const int wrow = wave * 16;
  const int lr   = l & 15;
  const int lkb  = (l >> 4) * 8;

  const float scale = 0.17677669529663687f;  // 1/sqrt(32), folded into Q

  // ---- stage Q tile (scale folded) ----
  {
    const int r = t >> 2, cb = (t & 3) * 8;
    const int qrow = q0 + r;
    unsigned short u[8];
    if (qrow < NQ_) {
      const float* src = &qhkh[(size_t)(b * NQ_ + qrow) * 512 + h * DH + cb];
      const float4 a0 = *reinterpret_cast<const float4*>(src);
      const float4 a1 = *reinterpret_cast<const float4*>(src + 4);
      u[0] = f2bf(a0.x * scale); u[1] = f2bf(a0.y * scale);
      u[2] = f2bf(a0.z * scale); u[3] = f2bf(a0.w * scale);
      u[4] = f2bf(a1.x * scale); u[5] = f2bf(a1.y * scale);
      u[6] = f2bf(a1.z * scale); u[7] = f2bf(a1.w * scale);
    } else {
#pragma unroll
      for (int j = 0; j < 8; ++j) u[j] = 0;
    }
    *reinterpret_cast<short8*>(&Qs[r][cb]) = *reinterpret_cast<short8*>(&u[0]);
  }
  __syncthreads();

  const short8 qa = *reinterpret_cast<const short8*>(&Qs[wrow + lr][lkb]);

  f32x4 oacc[2];
  oacc[0] = (f32x4)0.f; oacc[1] = (f32x4)0.f;
  float m_[4] = {-1e30f, -1e30f, -1e30f, -1e30f};
  float l_[4] = {0.f, 0.f, 0.f, 0.f};

  for (int kt = 0; kt < NQTM; ++kt) {
    const int k0 = kt * 64;
    const int nk = min(64, NQ_ - k0);
    __syncthreads();  // previous tile's readers done

    // ---- stage K tile (bf16) ----
    {
      const int r = t >> 2, cb = (t & 3) * 8;
      unsigned short u[8];
      if (r < nk) {
        const float* src = &qhkh[(size_t)(b * NQ_ + k0 + r) * 512 + 256 + h * DH + cb];
        const float4 a0 = *reinterpret_cast<const float4*>(src);
        const float4 a1 = *reinterpret_cast<const float4*>(src + 4);
        u[0] = f2bf(a0.x); u[1] = f2bf(a0.y); u[2] = f2bf(a0.z); u[3] = f2bf(a0.w);
        u[4] = f2bf(a1.x); u[5] = f2bf(a1.y); u[6] = f2bf(a1.z); u[7] = f2bf(a1.w);
      } else {
#pragma unroll
        for (int j = 0; j < 8; ++j) u[j] = 0;
      }
      *reinterpret_cast<short8*>(&Ks[r][cb]) = *reinterpret_cast<short8*>(&u[0]);
    }
    // ---- stage V^T tile (bf16) ----
    {
      const int k = t & 63, db = (t >> 6) * 8;
      float vv[8];
      if (k < nk) {
        const float* src = &vh[(size_t)(b * NQ_ + k0 + k) * D_ + h * DH + db];
        const float4 a0 = *reinterpret_cast<const float4*>(src);
        const float4 a1 = *reinterpret_cast<const float4*>(src + 4);
        vv[0] = a0.x; vv[1] = a0.y; vv[2] = a0.z; vv[3] = a0.w;
        vv[4] = a1.x; vv[5] = a1.y; vv[6] = a1.z; vv[7] = a1.w;
      } else {
#pragma unroll
        for (int j = 0; j < 8; ++j) vv[j] = 0.f;
      }
#pragma unroll
      for (int j = 0; j < 8; ++j) Vts[db + j][k] = f2bf(vv[j]);
    }
    __syncthreads();

    // ---- S = Q K^T (scaled) ----
    f32x4 sacc[4];
#pragma unroll
    for (int fj = 0; fj < 4; ++fj)
      sacc[fj] = __builtin_amdgcn_mfma_f32_16x16x32_bf16(
          qa, *reinterpret_cast<const short8*>(&Ks[16 * fj + lr][lkb]),
          (f32x4)0.f, 0, 0, 0);

    // col validity (same for all i within a lane)
    bool cv[4];
#pragma unroll
    for (int fj = 0; fj < 4; ++fj) cv[fj] = (16 * fj + lr) < nk;

    // ---- online softmax (rows in i-index, cols across 16-lane group) ----
    float p0[4], p1[4], p2[4], p3[4], sc_[4];
#pragma unroll
    for (int i = 0; i < 4; ++i) {
      float tm = -1e30f;
      if (cv[0]) tm = fmaxf(tm, sacc[0][i]);
      if (cv[1]) tm = fmaxf(tm, sacc[1][i]);
      if (cv[2]) tm = fmaxf(tm, sacc[2][i]);
      if (cv[3]) tm = fmaxf(tm, sacc[3][i]);
      tm = fmaxf(tm, __shfl_xor(tm, 1));
      tm = fmaxf(tm, __shfl_xor(tm, 2));
      tm = fmaxf(tm, __shfl_xor(tm, 4));
      tm = fmaxf(tm, __shfl_xor(tm, 8));
      const float mn = fmaxf(m_[i], tm);
      sc_[i] = __expf(m_[i] - mn);
      m_[i] = mn;
      const float e0 = cv[0] ? __expf(sacc[0][i] - mn) : 0.f;
      const float e1 = cv[1] ? __expf(sacc[1][i] - mn) : 0.f;
      const float e2 = cv[2] ? __expf(sacc[2][i] - mn) : 0.f;
      const float e3 = cv[3] ? __expf(sacc[3][i] - mn) : 0.f;
      p0[i] = e0; p1[i] = e1; p2[i] = e2; p3[i] = e3;
      float rs = e0 + e1 + e2 + e3;
      rs += __shfl_xor(rs, 1);
      rs += __shfl_xor(rs, 2);
      rs += __shfl_xor(rs, 4);
      rs += __shfl_xor(rs, 8);
      l_[i] = l_[i] * sc_[i] + rs;
    }

    // ---- P -> LDS (bf16), wave-private rows ----
#pragma unroll
    for (int i = 0; i < 4; ++i) {
      const int pr = wrow + (l >> 4) * 4 + i;
      Ps[pr][0  + lr] = f2bf(p0[i]);
      Ps[pr][16 + lr] = f2bf(p1[i]);
      Ps[pr][32 + lr] = f2bf(p2[i]);
      Ps[pr][48 + lr] = f2bf(p3[i]);
    }
    __syncthreads();

    // ---- PV ----
    const short8 pa0 = *reinterpret_cast<const short8*>(&Ps[wrow + lr][lkb]);
    const short8 pa1 = *reinterpret_cast<const short8*>(&Ps[wrow + lr][lkb + 32]);
#pragma unroll
    for (int nt = 0; nt < 2; ++nt) {
      f32x4 c = oacc[nt];
#pragma unroll
      for (int i = 0; i < 4; ++i) c[i] *= sc_[i];
      c = __builtin_amdgcn_mfma_f32_16x16x32_bf16(
          pa0, *reinterpret_cast<const short8*>(&Vts[16 * nt + lr][lkb]), c, 0, 0, 0);
      c = __builtin_amdgcn_mfma_f32_16x16x32_bf16(
          pa1, *reinterpret_cast<const short8*>(&Vts[16 * nt + lr][lkb + 32]), c, 0, 0, 0);
      oacc[nt] = c;
    }
  }

  // ---- epilogue ----
#pragma unroll
  for (int i = 0; i < 4; ++i) {
    const int r = (l >> 4) * 4 + i;
    const int q = q0 + wrow + r;
    if (q < NQ_) {
      const float inv = 1.f / l_[i];
      o[(size_t)(b * NQ_ + q) * D_ + h * DH + 0  + lr] = oacc[0][i] * inv;
      o[(size_t)(b * NQ_ + q) * D_ + h * DH + 16 + lr] = oacc[1][i] * inv;
    }
  }
}

// ---------------------------------------------------------------------------
// out = LayerNorm(res + add) * g + b
// ---------------------------------------------------------------------------
__global__ __launch_bounds__(256) void ln(const float* __restrict__ res,
                                          const float* __restrict__ add,
                                          const float* __restrict__ g,
                                          const float* __restrict__ bt,
                                          float* __restrict__ out) {
  __shared__ float red[256];
  const int r = blockIdx.x, t = threadIdx.x;
  const float x = res[r * D_ + t] + add[r * D_ + t];
  red[t] = x;
  __syncthreads();
  for (int s = 128; s > 0; s >>= 1) {
    if (t < s) red[t] += red[t + s];
    __syncthreads();
  }
  const float mean = red[0] * (1.f / D_);
  __syncthreads();
  const float dx = x - mean;
  red[t] = dx * dx;
  __syncthreads();
  for (int s = 128; s > 0; s >>= 1) {
    if (t < s) red[t] += red[t + s];
    __syncthreads();
  }
  const float var = red[0] * (1.f / D_);
  out[r * D_ + t] = dx * rsqrtf(var + 1e-5f) * g[t] + bt[t];
}

// ---------------------------------------------------------------------------
extern "C" void kernel_launch(void* const* d_in, const int* in_sizes, int n_in,
                              void* d_out, int out_size, void* d_ws,
                              size_t ws_size, hipStream_t stream) {
  const float* tgt   = (const float*)d_in[0];
  const float* pos   = (const float*)d_in[1];
  const float* refp  = (const float*)d_in[2];
  const float* mem   = (const float*)d_in[3];
  const float* Wv    = (const float*)d_in[4];
  const float* bv    = (const float*)d_in[5];
  const float* Wo    = (const float*)d_in[6];
  const float* bo    = (const float*)d_in[7];
  const float* Wa    = (const float*)d_in[8];
  const float* ba    = (const float*)d_in[9];
  const float* Wca   = (const float*)d_in[10];
  const float* bca   = (const float*)d_in[11];
  const float* g1    = (const float*)d_in[12];
  const float* b1    = (const float*)d_in[13];
  const float* Win   = (const float*)d_in[14];
  const float* bin   = (const float*)d_in[15];
  const float* Wsa   = (const float*)d_in[16];
  const float* bsa   = (const float*)d_in[17];
  const float* g2    = (const float*)d_in[18];
  const float* b2    = (const float*)d_in[19];
  const float* W1    = (const float*)d_in[20];
  const float* bb1   = (const float*)d_in[21];
  const float* W2    = (const float*)d_in[22];
  const float* bb2   = (const float*)d_in[23];
  const float* g3    = (const float*)d_in[24];
  const float* b3    = (const float*)d_in[25];

  float* ws = (float*)d_ws;
  float* v      = ws;              ws += MV * D_;
  float* q      = ws;              ws += MQ * D_;
  float* off    = ws;              ws += MQ * D_;
  float* logits = ws;              ws += MQ * 128;
  float* accb   = ws;              ws += MQ * D_;
  float* tmp    = ws;              ws += MQ * D_;
  float* x1     = ws;              ws += MQ * D_;
  float* qk     = ws;              ws += MQ * D_;
  float* qhkh   = ws;              ws += MQ * 512;
  float* vh     = ws;              ws += MQ * D_;
  float* obuf   = ws;              ws += MQ * D_;
  float* x2     = ws;              ws += MQ * D_;
  float* h1     = ws;              ws += MQ * DFF_;
  unsigned short* wb = (unsigned short*)ws;
  unsigned short* Wv_bf  = wb;  wb += 256 * 256;
  unsigned short* Wo_bf  = wb;  wb += 256 * 256;
  unsigned short* Wa_bf  = wb;  wb += 128 * 256;
  unsigned short* Wca_bf = wb;  wb += 256 * 256;
  unsigned short* Win_bf = wb;  wb += 768 * 256;
  unsigned short* Wsa_bf = wb;  wb += 256 * 256;
  unsigned short* W1_bf  = wb;  wb += 1024 * 256;
  unsigned short* W2_bf  = wb;  wb += 256 * 1024;

  CvtArgs ca;
  ca.src[0] = Wv;  ca.dst[0] = Wv_bf;  ca.n[0] = 256 * 256;
  ca.src[1] = Wo;  ca.dst[1] = Wo_bf;  ca.n[1] = 256 * 256;
  ca.src[2] = Wa;  ca.dst[2] = Wa_bf;  ca.n[2] = 128 * 256;
  ca.src[3] = Wca; ca.dst[3] = Wca_bf; ca.n[3] = 256 * 256;
  ca.src[4] = Win; ca.dst[4] = Win_bf; ca.n[4] = 768 * 256;
  ca.src[5] = Wsa; ca.dst[5] = Wsa_bf; ca.n[5] = 256 * 256;
  ca.src[6] = W1;  ca.dst[6] = W1_bf;  ca.n[6] = 1024 * 256;
  ca.src[7] = W2;  ca.dst[7] = W2_bf;  ca.n[7] = 256 * 1024;
  cvtw<<<dim3(64, 8), 256, 0, stream>>>(ca);

  const int mqb = (MQ + 127) / 128;   // 29
  const int mvb = (MV + 127) / 128;   // 665

  gemm_mfma<false><<<dim3(256 / 128, mvb), 256, 0, stream>>>(mem, Wv_bf, bv, v,
                                                             MV, 256, 256);
  add2<<<(MQ * D_ + 255) / 256, 256, 0, stream>>>(tgt, pos, q, MQ * D_);
  gemm_mfma<false><<<dim3(256 / 128, mqb), 256, 0, stream>>>(q, Wo_bf, bo, off,
                                                             MQ, 256, 256);
  gemm_mfma<false><<<dim3(128 / 128, mqb), 256, 0, stream>>>(q, Wa_bf, ba,
                                                             logits, MQ, 128, 256);
  deform<<<MQ, 256, 0, stream>>>(refp, off, logits, v, accb);
  gemm_mfma<false><<<dim3(256 / 128, mqb), 256, 0, stream>>>(accb, Wca_bf, bca,
                                                             tmp, MQ, 256, 256);
  ln<<<MQ, 256, 0, stream>>>(tgt, tmp, g1, b1, x1);
  add2<<<(MQ * D_ + 255) / 256, 256, 0, stream>>>(x1, pos, qk, MQ * D_);
  gemm_mfma<false><<<dim3(512 / 128, mqb), 256, 0, stream>>>(qk, Win_bf, bin,
                                                             qhkh, MQ, 512, 256);
  gemm_mfma<false><<<dim3(256 / 128, mqb), 256, 0, stream>>>(
      x1, Win_bf + 512 * 256, bin + 512, vh, MQ, 256, 256);
  mha_mfma<<<B_ * H_ * NQTM, 256, 0, stream>>>(qhkh, vh, obuf);
  gemm_mfma<false><<<dim3(256 / 128, mqb), 256, 0, stream>>>(obuf, Wsa_bf, bsa,
                                                             tmp, MQ, 256, 256);
  ln<<<MQ, 256, 0, stream>>>(x1, tmp, g2, b2, x2);
  gemm_mfma<true><<<dim3(1024 / 128, mqb), 256, 0, stream>>>(x2, W1_bf, bb1, h1,
                                                             MQ, 1024, 256);
  gemm_mfma<false><<<dim3(256 / 128, mqb), 256, 0, stream>>>(h1, W2_bf, bb2,
                                                             tmp, MQ, 256, 1024);
  ln<<<MQ, 256, 0, stream>>>(x2, tmp, g3, b3, (float*)d_out);
}

// Round 5
// 255.078 us; speedup vs baseline: 3.8257x; 1.1926x over previous
//
#include <hip/hip_runtime.h>

constexpr int D_   = 256;
constexpr int H_   = 8;
constexpr int DH   = 32;
constexpr int L_   = 4;
constexpr int P_   = 4;
constexpr int DFF_ = 1024;
constexpr int B_   = 4;
constexpr int NQ_  = 900;
constexpr int NV_  = 21260;
constexpr int MQ   = B_ * NQ_;   // 3600
constexpr int MV   = B_ * NV_;   // 85040

typedef __attribute__((ext_vector_type(8))) short short8;
typedef __attribute__((ext_vector_type(4))) float f32x4;

static __device__ __forceinline__ unsigned short f2bf(float x) {
  union { float f; unsigned int u; } v;
  v.f = x;
  const unsigned int r = v.u + 0x7fffu + ((v.u >> 16) & 1u);
  return (unsigned short)(r >> 16);
}
static __device__ __forceinline__ float bf2f(unsigned short u) {
  union { unsigned int i; float f; } x;
  x.i = ((unsigned int)u) << 16;
  return x.f;
}

// ---------------------------------------------------------------------------
// Weight conversion: 9 segments f32 -> bf16 (optional scale), one launch.
// ---------------------------------------------------------------------------
struct CvtArgs {
  const float* src[9];
  unsigned short* dst[9];
  int n[9];
  float scl[9];
};

__global__ __launch_bounds__(256) void cvtw(CvtArgs a) {
  const int seg = blockIdx.y;
  const int n = a.n[seg];
  const float s = a.scl[seg];
  const float* __restrict__ sp = a.src[seg];
  unsigned short* __restrict__ d = a.dst[seg];
  for (int i = (blockIdx.x * 256 + threadIdx.x) * 4; i < n;
       i += gridDim.x * 256 * 4) {
    const float4 v = *reinterpret_cast<const float4*>(&sp[i]);
    d[i + 0] = f2bf(v.x * s); d[i + 1] = f2bf(v.y * s);
    d[i + 2] = f2bf(v.z * s); d[i + 3] = f2bf(v.w * s);
  }
}

// biasqk[512]: Q part scaled by 1/sqrt(32); bfused[384] = [bo | ba]
__global__ void biasprep(const float* __restrict__ bin,
                         const float* __restrict__ bo,
                         const float* __restrict__ ba,
                         float* __restrict__ bqk, float* __restrict__ bfu) {
  const int i = threadIdx.x;
  if (i < 512) bqk[i] = (i < 256) ? bin[i] * 0.17677669529663687f : bin[i];
  if (i < 384) bfu[i] = (i < 256) ? bo[i] : ba[i - 256];
}

// ---------------------------------------------------------------------------
// Double-buffered MFMA bf16 GEMM. C[M,N] = A[M,K] @ W[N,K]^T + bias.
// BM=BN=128, BK=32, 256 thr = 4 waves, wave tile 64x64, 1 barrier/K-step.
// ABF: A is bf16 (else f32, converted in staging). ADD2: A := A + A2 (f32).
// OUTBF: write bf16 output.
// ---------------------------------------------------------------------------
template <bool ABF, bool ADD2, bool RELU, bool OUTBF>
__global__ __launch_bounds__(256) void gemm_db(
    const void* __restrict__ Ap, const float* __restrict__ A2,
    const unsigned short* __restrict__ Wbf, const float* __restrict__ bias,
    void* __restrict__ Cp, int M, int N, int K) {
  constexpr int LDR = 40;
  __shared__ unsigned short As[2][128][LDR];
  __shared__ unsigned short Bs[2][128][LDR];

  const float* Af = (const float*)Ap;
  const unsigned short* Ab = (const unsigned short*)Ap;
  float* Cf = (float*)Cp;
  unsigned short* Cb = (unsigned short*)Cp;

  const int t    = threadIdx.x;
  const int wave = t >> 6;
  const int l    = t & 63;
  const int n0   = blockIdx.x * 128;
  const int m0   = blockIdx.y * 128;
  const int wm   = (wave >> 1) * 64;
  const int wn   = (wave & 1) * 64;
  const int srow = t >> 1;
  const int sseg = (t & 1) * 16;
  const int lr   = l & 15;
  const int lk   = (l >> 4) * 8;

  const int am = m0 + srow;
  const bool aok = am < M;
  const size_t arow = (size_t)am * K;
  const size_t brow = (size_t)(n0 + srow) * K;

  f32x4 acc[4][4];
#pragma unroll
  for (int i = 0; i < 4; ++i)
#pragma unroll
    for (int j = 0; j < 4; ++j) acc[i][j] = (f32x4)0.f;

  short8 ar0, ar1, br0, br1;

  auto LOAD = [&](int k0) {
    if constexpr (ABF) {
      if (aok) {
        ar0 = *reinterpret_cast<const short8*>(&Ab[arow + k0 + sseg]);
        ar1 = *reinterpret_cast<const short8*>(&Ab[arow + k0 + sseg + 8]);
      } else {
        ar0 = (short8)(short)0; ar1 = (short8)(short)0;
      }
    } else {
      if (aok) {
        float f[16];
#pragma unroll
        for (int j = 0; j < 4; ++j) {
          const float4 av =
              *reinterpret_cast<const float4*>(&Af[arow + k0 + sseg + 4 * j]);
          f[4 * j + 0] = av.x; f[4 * j + 1] = av.y;
          f[4 * j + 2] = av.z; f[4 * j + 3] = av.w;
        }
        if constexpr (ADD2) {
#pragma unroll
          for (int j = 0; j < 4; ++j) {
            const float4 av =
                *reinterpret_cast<const float4*>(&A2[arow + k0 + sseg + 4 * j]);
            f[4 * j + 0] += av.x; f[4 * j + 1] += av.y;
            f[4 * j + 2] += av.z; f[4 * j + 3] += av.w;
          }
        }
        alignas(16) unsigned short u[16];
#pragma unroll
        for (int j = 0; j < 16; ++j) u[j] = f2bf(f[j]);
        ar0 = *reinterpret_cast<short8*>(&u[0]);
        ar1 = *reinterpret_cast<short8*>(&u[8]);
      } else {
        ar0 = (short8)(short)0; ar1 = (short8)(short)0;
      }
    }
    br0 = *reinterpret_cast<const short8*>(&Wbf[brow + k0 + sseg]);
    br1 = *reinterpret_cast<const short8*>(&Wbf[brow + k0 + sseg + 8]);
  };

  const int nt = K >> 5;
  LOAD(0);
  for (int tt = 0; tt < nt; ++tt) {
    const int cur = tt & 1;
    *reinterpret_cast<short8*>(&As[cur][srow][sseg])     = ar0;
    *reinterpret_cast<short8*>(&As[cur][srow][sseg + 8]) = ar1;
    *reinterpret_cast<short8*>(&Bs[cur][srow][sseg])     = br0;
    *reinterpret_cast<short8*>(&Bs[cur][srow][sseg + 8]) = br1;
    if (tt + 1 < nt) LOAD((tt + 1) << 5);
    __syncthreads();

    short8 af[4], bfr[4];
#pragma unroll
    for (int fi = 0; fi < 4; ++fi)
      af[fi] = *reinterpret_cast<const short8*>(&As[cur][wm + fi * 16 + lr][lk]);
#pragma unroll
    for (int fj = 0; fj < 4; ++fj)
      bfr[fj] = *reinterpret_cast<const short8*>(&Bs[cur][wn + fj * 16 + lr][lk]);

#pragma unroll
    for (int fi = 0; fi < 4; ++fi)
#pragma unroll
      for (int fj = 0; fj < 4; ++fj)
        acc[fi][fj] = __builtin_amdgcn_mfma_f32_16x16x32_bf16(
            af[fi], bfr[fj], acc[fi][fj], 0, 0, 0);
  }

  const int orow = (l >> 4) * 4;
#pragma unroll
  for (int fi = 0; fi < 4; ++fi) {
#pragma unroll
    for (int fj = 0; fj < 4; ++fj) {
      const int n = n0 + wn + fj * 16 + lr;
      const float bn = bias[n];
#pragma unroll
      for (int i = 0; i < 4; ++i) {
        const int m = m0 + wm + fi * 16 + orow + i;
        if (m < M) {
          float vv = acc[fi][fj][i] + bn;
          if (RELU) vv = fmaxf(vv, 0.f);
          if (OUTBF)
            Cb[(size_t)m * N + n] = f2bf(vv);
          else
            Cf[(size_t)m * N + n] = vv;
        }
      }
    }
  }
}

// ---------------------------------------------------------------------------
// Deformable sampling. One block (256 thr) per (b,q). tid = h*32 + d.
// off+logits fused in offlog[MQ][384] (off: cols 0..255, logits: 256..383).
// v is bf16.
// ---------------------------------------------------------------------------
__global__ __launch_bounds__(256) void deform(const float* __restrict__ refp,
                                              const float* __restrict__ offlog,
                                              const unsigned short* __restrict__ v,
                                              float* __restrict__ acc) {
  __shared__ float aw[H_ * L_ * P_];
  const int bq = blockIdx.x;
  const int b  = bq / NQ_;
  const int t  = threadIdx.x;
  const int h  = t >> 5, d = t & 31;

  if (t < 128) aw[t] = offlog[(size_t)bq * 384 + 256 + t];
  __syncthreads();
  if (t < 8) {
    float mx = -1e30f;
#pragma unroll
    for (int i = 0; i < 16; ++i) mx = fmaxf(mx, aw[t * 16 + i]);
    float e[16], s = 0.f;
#pragma unroll
    for (int i = 0; i < 16; ++i) { e[i] = expf(aw[t * 16 + i] - mx); s += e[i]; }
    const float inv = 1.f / s;
#pragma unroll
    for (int i = 0; i < 16; ++i) aw[t * 16 + i] = e[i] * inv;
  }
  __syncthreads();

  constexpr int ST[4] = {0, 16000, 20000, 21000};
  constexpr int HL[4] = {100, 50, 25, 13};
  constexpr int WL[4] = {160, 80, 40, 20};

  float a = 0.f;
#pragma unroll
  for (int l = 0; l < L_; ++l) {
    const float rx = refp[(bq * L_ + l) * 2 + 0];
    const float ry = refp[(bq * L_ + l) * 2 + 1];
    const float Wf = (float)WL[l], Hf = (float)HL[l];
    const int   Wi = WL[l], Hi = HL[l];
    const int vbase = (b * NV_ + ST[l]) * D_ + h * DH + d;
#pragma unroll
    for (int p = 0; p < P_; ++p) {
      const float ox = offlog[(size_t)bq * 384 + h * 32 + l * 8 + p * 2 + 0];
      const float oy = offlog[(size_t)bq * 384 + h * 32 + l * 8 + p * 2 + 1];
      const float locx = rx + ox / Wf;
      const float locy = ry + oy / Hf;
      const float xl = locx * Wf - 0.5f;
      const float yl = locy * Hf - 0.5f;
      const float x0 = floorf(xl), y0 = floorf(yl);
      const float wx = xl - x0, wy = yl - y0;
      const int x0i = (int)x0, y0i = (int)y0;
      const float w = aw[h * 16 + l * 4 + p];

      float s = 0.f;
#pragma unroll
      for (int c = 0; c < 4; ++c) {
        const int xi = x0i + (c & 1);
        const int yi = y0i + (c >> 1);
        const float cw = ((c & 1) ? wx : 1.f - wx) * ((c >> 1) ? wy : 1.f - wy);
        const bool valid = (xi >= 0) && (xi < Wi) && (yi >= 0) && (yi < Hi);
        const int xc = min(max(xi, 0), Wi - 1);
        const int yc = min(max(yi, 0), Hi - 1);
        const float g = bf2f(v[vbase + (yc * Wi + xc) * D_]);
        s += valid ? g * cw : 0.f;
      }
      a += w * s;
    }
  }
  acc[bq * D_ + t] = a;
}

// ---------------------------------------------------------------------------
// MFMA flash MHA (bf16 inputs; QK-scale pre-folded into Q projection).
// ---------------------------------------------------------------------------
constexpr int TQM  = 64;
constexpr int NQTM = (NQ_ + TQM - 1) / TQM;   // 15

__global__ __launch_bounds__(256) void mha_mfma(
    const unsigned short* __restrict__ qkh,
    const unsigned short* __restrict__ vh,
    unsigned short* __restrict__ o) {
  __shared__ unsigned short Qs[64][40];
  __shared__ unsigned short Ks[64][40];
  __shared__ unsigned short Vts[32][72];
  __shared__ unsigned short Ps[64][72];

  const int bx = blockIdx.x;
  const int qt = bx % NQTM;
  const int h  = (bx / NQTM) % H_;
  const int b  = bx / (NQTM * H_);
  const int t  = threadIdx.x;
  const int wave = t >> 6;
  const int l    = t & 63;
  const int q0   = qt * TQM;
  const int wrow = wave * 16;
  const int lr   = l & 15;
  const int lkb  = (l >> 4) * 8;

  // ---- stage Q tile ----
  {
    const int r = t >> 2, cb = (t & 3) * 8;
    short8 u;
    if (q0 + r < NQ_)
      u = *reinterpret_cast<const short8*>(
          &qkh[(size_t)(b * NQ_ + q0 + r) * 512 + h * DH + cb]);
    else
      u = (short8)(short)0;
    *reinterpret_cast<short8*>(&Qs[r][cb]) = u;
  }
  __syncthreads();

  const short8 qa = *reinterpret_cast<const short8*>(&Qs[wrow + lr][lkb]);

  f32x4 oacc[2];
  oacc[0] = (f32x4)0.f; oacc[1] = (f32x4)0.f;
  float m_[4] = {-1e30f, -1e30f, -1e30f, -1e30f};
  float l_[4] = {0.f, 0.f, 0.f, 0.f};

  for (int kt = 0; kt < NQTM; ++kt) {
    const int k0 = kt * 64;
    const int nk = min(64, NQ_ - k0);
    __syncthreads();

    // ---- stage K tile ----
    {
      const int r = t >> 2, cb = (t & 3) * 8;
      short8 u;
      if (r < nk)
        u = *reinterpret_cast<const short8*>(
            &qkh[(size_t)(b * NQ_ + k0 + r) * 512 + 256 + h * DH + cb]);
      else
        u = (short8)(short)0;
      *reinterpret_cast<short8*>(&Ks[r][cb]) = u;
    }
    // ---- stage V^T tile ----
    {
      const int k = t & 63, db = (t >> 6) * 8;
      short8 u;
      if (k < nk)
        u = *reinterpret_cast<const short8*>(
            &vh[(size_t)(b * NQ_ + k0 + k) * D_ + h * DH + db]);
      else
        u = (short8)(short)0;
#pragma unroll
      for (int j = 0; j < 8; ++j) Vts[db + j][k] = (unsigned short)u[j];
    }
    __syncthreads();

    // ---- S = Q K^T ----
    f32x4 sacc[4];
#pragma unroll
    for (int fj = 0; fj < 4; ++fj)
      sacc[fj] = __builtin_amdgcn_mfma_f32_16x16x32_bf16(
          qa, *reinterpret_cast<const short8*>(&Ks[16 * fj + lr][lkb]),
          (f32x4)0.f, 0, 0, 0);

    bool cv[4];
#pragma unroll
    for (int fj = 0; fj < 4; ++fj) cv[fj] = (16 * fj + lr) < nk;

    float p0[4], p1[4], p2[4], p3[4], sc_[4];
#pragma unroll
    for (int i = 0; i < 4; ++i) {
      float tm = -1e30f;
      if (cv[0]) tm = fmaxf(tm, sacc[0][i]);
      if (cv[1]) tm = fmaxf(tm, sacc[1][i]);
      if (cv[2]) tm = fmaxf(tm, sacc[2][i]);
      if (cv[3]) tm = fmaxf(tm, sacc[3][i]);
      tm = fmaxf(tm, __shfl_xor(tm, 1));
      tm = fmaxf(tm, __shfl_xor(tm, 2));
      tm = fmaxf(tm, __shfl_xor(tm, 4));
      tm = fmaxf(tm, __shfl_xor(tm, 8));
      const float mn = fmaxf(m_[i], tm);
      sc_[i] = __expf(m_[i] - mn);
      m_[i] = mn;
      const float e0 = cv[0] ? __expf(sacc[0][i] - mn) : 0.f;
      const float e1 = cv[1] ? __expf(sacc[1][i] - mn) : 0.f;
      const float e2 = cv[2] ? __expf(sacc[2][i] - mn) : 0.f;
      const float e3 = cv[3] ? __expf(sacc[3][i] - mn) : 0.f;
      p0[i] = e0; p1[i] = e1; p2[i] = e2; p3[i] = e3;
      float rs = e0 + e1 + e2 + e3;
      rs += __shfl_xor(rs, 1);
      rs += __shfl_xor(rs, 2);
      rs += __shfl_xor(rs, 4);
      rs += __shfl_xor(rs, 8);
      l_[i] = l_[i] * sc_[i] + rs;
    }

#pragma unroll
    for (int i = 0; i < 4; ++i) {
      const int pr = wrow + (l >> 4) * 4 + i;
      Ps[pr][0  + lr] = f2bf(p0[i]);
      Ps[pr][16 + lr] = f2bf(p1[i]);
      Ps[pr][32 + lr] = f2bf(p2[i]);
      Ps[pr][48 + lr] = f2bf(p3[i]);
    }
    __syncthreads();

    const short8 pa0 = *reinterpret_cast<const short8*>(&Ps[wrow + lr][lkb]);
    const short8 pa1 = *reinterpret_cast<const short8*>(&Ps[wrow + lr][lkb + 32]);
#pragma unroll
    for (int nt = 0; nt < 2; ++nt) {
      f32x4 c = oacc[nt];
#pragma unroll
      for (int i = 0; i < 4; ++i) c[i] *= sc_[i];
      c = __builtin_amdgcn_mfma_f32_16x16x32_bf16(
          pa0, *reinterpret_cast<const short8*>(&Vts[16 * nt + lr][lkb]), c, 0, 0, 0);
      c = __builtin_amdgcn_mfma_f32_16x16x32_bf16(
          pa1, *reinterpret_cast<const short8*>(&Vts[16 * nt + lr][lkb + 32]), c, 0, 0, 0);
      oacc[nt] = c;
    }
  }

#pragma unroll
  for (int i = 0; i < 4; ++i) {
    const int r = (l >> 4) * 4 + i;
    const int q = q0 + wrow + r;
    if (q < NQ_) {
      const float inv = 1.f / l_[i];
      o[(size_t)(b * NQ_ + q) * D_ + h * DH + 0  + lr] = f2bf(oacc[0][i] * inv);
      o[(size_t)(b * NQ_ + q) * D_ + h * DH + 16 + lr] = f2bf(oacc[1][i] * inv);
    }
  }
}

// ---------------------------------------------------------------------------
// out = LayerNorm(res + add) * g + b
// ---------------------------------------------------------------------------
__global__ __launch_bounds__(256) void ln(const float* __restrict__ res,
                                          const float* __restrict__ add,
                                          const float* __restrict__ g,
                                          const float* __restrict__ bt,
                                          float* __restrict__ out) {
  __shared__ float red[256];
  const int r = blockIdx.x, t = threadIdx.x;
  const float x = res[r * D_ + t] + add[r * D_ + t];
  red[t] = x;
  __syncthreads();
  for (int s = 128; s > 0; s >>= 1) {
    if (t < s) red[t] += red[t + s];
    __syncthreads();
  }
  const float mean = red[0] * (1.f / D_);
  __syncthreads();
  const float dx = x - mean;
  red[t] = dx * dx;
  __syncthreads();
  for (int s = 128; s > 0; s >>= 1) {
    if (t < s) red[t] += red[t + s];
    __syncthreads();
  }
  const float var = red[0] * (1.f / D_);
  out[r * D_ + t] = dx * rsqrtf(var + 1e-5f) * g[t] + bt[t];
}

// ---------------------------------------------------------------------------
extern "C" void kernel_launch(void* const* d_in, const int* in_sizes, int n_in,
                              void* d_out, int out_size, void* d_ws,
                              size_t ws_size, hipStream_t stream) {
  const float* tgt   = (const float*)d_in[0];
  const float* pos   = (const float*)d_in[1];
  const float* refp  = (const float*)d_in[2];
  const float* mem   = (const float*)d_in[3];
  const float* Wv    = (const float*)d_in[4];
  const float* bv    = (const float*)d_in[5];
  const float* Wo    = (const float*)d_in[6];
  const float* bo    = (const float*)d_in[7];
  const float* Wa    = (const float*)d_in[8];
  const float* ba    = (const float*)d_in[9];
  const float* Wca   = (const float*)d_in[10];
  const float* bca   = (const float*)d_in[11];
  const float* g1    = (const float*)d_in[12];
  const float* b1    = (const float*)d_in[13];
  const float* Win   = (const float*)d_in[14];
  const float* bin   = (const float*)d_in[15];
  const float* Wsa   = (const float*)d_in[16];
  const float* bsa   = (const float*)d_in[17];
  const float* g2    = (const float*)d_in[18];
  const float* b2    = (const float*)d_in[19];
  const float* W1    = (const float*)d_in[20];
  const float* bb1   = (const float*)d_in[21];
  const float* W2    = (const float*)d_in[22];
  const float* bb2   = (const float*)d_in[23];
  const float* g3    = (const float*)d_in[24];
  const float* b3    = (const float*)d_in[25];

  char* cur = (char*)d_ws;
  auto alloc = [&](size_t bytes) {
    char* p = cur;
    cur += (bytes + 255) & ~(size_t)255;
    return (void*)p;
  };
  unsigned short* v_bf    = (unsigned short*)alloc((size_t)MV * 256 * 2);
  float*          offlog  = (float*)alloc((size_t)MQ * 384 * 4);
  float*          accb    = (float*)alloc((size_t)MQ * 256 * 4);
  float*          tmp     = (float*)alloc((size_t)MQ * 256 * 4);
  float*          x1      = (float*)alloc((size_t)MQ * 256 * 4);
  float*          x2      = (float*)alloc((size_t)MQ * 256 * 4);
  unsigned short* qkh_bf  = (unsigned short*)alloc((size_t)MQ * 512 * 2);
  unsigned short* vh_bf   = (unsigned short*)alloc((size_t)MQ * 256 * 2);
  unsigned short* obuf_bf = (unsigned short*)alloc((size_t)MQ * 256 * 2);
  unsigned short* h1_bf   = (unsigned short*)alloc((size_t)MQ * 1024 * 2);
  unsigned short* Wv_bf   = (unsigned short*)alloc(65536 * 2);
  unsigned short* Wfu_bf  = (unsigned short*)alloc(98304 * 2);   // [Wo|Wa]
  unsigned short* Wca_bf  = (unsigned short*)alloc(65536 * 2);
  unsigned short* Win_bf  = (unsigned short*)alloc(196608 * 2);
  unsigned short* Wsa_bf  = (unsigned short*)alloc(65536 * 2);
  unsigned short* W1_bf   = (unsigned short*)alloc(262144 * 2);
  unsigned short* W2_bf   = (unsigned short*)alloc(262144 * 2);
  float*          biasqk  = (float*)alloc(512 * 4);
  float*          bfused  = (float*)alloc(384 * 4);

  const float qscale = 0.17677669529663687f;  // 1/sqrt(32)

  CvtArgs ca;
  ca.src[0] = Wv;            ca.dst[0] = Wv_bf;          ca.n[0] = 65536;  ca.scl[0] = 1.f;
  ca.src[1] = Wo;            ca.dst[1] = Wfu_bf;         ca.n[1] = 65536;  ca.scl[1] = 1.f;
  ca.src[2] = Wa;            ca.dst[2] = Wfu_bf + 65536; ca.n[2] = 32768;  ca.scl[2] = 1.f;
  ca.src[3] = Wca;           ca.dst[3] = Wca_bf;         ca.n[3] = 65536;  ca.scl[3] = 1.f;
  ca.src[4] = Win;           ca.dst[4] = Win_bf;         ca.n[4] = 65536;  ca.scl[4] = qscale;
  ca.src[5] = Win + 65536;   ca.dst[5] = Win_bf + 65536; ca.n[5] = 131072; ca.scl[5] = 1.f;
  ca.src[6] = Wsa;           ca.dst[6] = Wsa_bf;         ca.n[6] = 65536;  ca.scl[6] = 1.f;
  ca.src[7] = W1;            ca.dst[7] = W1_bf;          ca.n[7] = 262144; ca.scl[7] = 1.f;
  ca.src[8] = W2;            ca.dst[8] = W2_bf;          ca.n[8] = 262144; ca.scl[8] = 1.f;
  cvtw<<<dim3(64, 9), 256, 0, stream>>>(ca);
  biasprep<<<1, 512, 0, stream>>>(bin, bo, ba, biasqk, bfused);

  const int mqb = (MQ + 127) / 128;   // 29
  const int mvb = (MV + 127) / 128;   // 665

  // value projection -> bf16
  gemm_db<false, false, false, true><<<dim3(2, mvb), 256, 0, stream>>>(
      mem, nullptr, Wv_bf, bv, v_bf, MV, 256, 256);
  // (tgt+pos) @ [Wo|Wa] -> offlog f32
  gemm_db<false, true, false, false><<<dim3(3, mqb), 256, 0, stream>>>(
      tgt, pos, Wfu_bf, bfused, offlog, MQ, 384, 256);
  deform<<<MQ, 256, 0, stream>>>(refp, offlog, v_bf, accb);
  gemm_db<false, false, false, false><<<dim3(2, mqb), 256, 0, stream>>>(
      accb, nullptr, Wca_bf, bca, tmp, MQ, 256, 256);
  ln<<<MQ, 256, 0, stream>>>(tgt, tmp, g1, b1, x1);
  // (x1+pos) @ Win[QK] -> qkh bf16 (Q pre-scaled)
  gemm_db<false, true, false, true><<<dim3(4, mqb), 256, 0, stream>>>(
      x1, pos, Win_bf, biasqk, qkh_bf, MQ, 512, 256);
  // x1 @ Win[V] -> vh bf16
  gemm_db<false, false, false, true><<<dim3(2, mqb), 256, 0, stream>>>(
      x1, nullptr, Win_bf + 512 * 256, bin + 512, vh_bf, MQ, 256, 256);
  mha_mfma<<<B_ * H_ * NQTM, 256, 0, stream>>>(qkh_bf, vh_bf, obuf_bf);
  gemm_db<true, false, false, false><<<dim3(2, mqb), 256, 0, stream>>>(
      obuf_bf, nullptr, Wsa_bf, bsa, tmp, MQ, 256, 256);
  ln<<<MQ, 256, 0, stream>>>(x1, tmp, g2, b2, x2);
  gemm_db<false, false, true, true><<<dim3(8, mqb), 256, 0, stream>>>(
      x2, nullptr, W1_bf, bb1, h1_bf, MQ, 1024, 256);
  gemm_db<true, false, false, false><<<dim3(2, mqb), 256, 0, stream>>>(
      h1_bf, nullptr, W2_bf, bb2, tmp, MQ, 256, 1024);
  ln<<<MQ, 256, 0, stream>>>(x2, tmp, g3, b3, (float*)d_out);
}

// Round 6
// 253.477 us; speedup vs baseline: 3.8499x; 1.0063x over previous
//
#include <hip/hip_runtime.h>

constexpr int D_   = 256;
constexpr int H_   = 8;
constexpr int DH   = 32;
constexpr int L_   = 4;
constexpr int P_   = 4;
constexpr int DFF_ = 1024;
constexpr int B_   = 4;
constexpr int NQ_  = 900;
constexpr int NV_  = 21260;
constexpr int MQ   = B_ * NQ_;   // 3600
constexpr int MV   = B_ * NV_;   // 85040

typedef __attribute__((ext_vector_type(8))) short short8;
typedef __attribute__((ext_vector_type(4))) float f32x4;

static __device__ __forceinline__ unsigned short f2bf(float x) {
  union { float f; unsigned int u; } v;
  v.f = x;
  const unsigned int r = v.u + 0x7fffu + ((v.u >> 16) & 1u);
  return (unsigned short)(r >> 16);
}
static __device__ __forceinline__ float bf2f(unsigned short u) {
  union { unsigned int i; float f; } x;
  x.i = ((unsigned int)u) << 16;
  return x.f;
}

// ---------------------------------------------------------------------------
// Weight conversion: 9 segments f32 -> bf16 (optional scale), one launch.
// ---------------------------------------------------------------------------
struct CvtArgs {
  const float* src[9];
  unsigned short* dst[9];
  int n[9];
  float scl[9];
};

__global__ __launch_bounds__(256) void cvtw(CvtArgs a) {
  const int seg = blockIdx.y;
  const int n = a.n[seg];
  const float s = a.scl[seg];
  const float* __restrict__ sp = a.src[seg];
  unsigned short* __restrict__ d = a.dst[seg];
  for (int i = (blockIdx.x * 256 + threadIdx.x) * 4; i < n;
       i += gridDim.x * 256 * 4) {
    const float4 v = *reinterpret_cast<const float4*>(&sp[i]);
    d[i + 0] = f2bf(v.x * s); d[i + 1] = f2bf(v.y * s);
    d[i + 2] = f2bf(v.z * s); d[i + 3] = f2bf(v.w * s);
  }
}

// biasqk[512]: Q part scaled by 1/sqrt(32); bfused[384] = [bo | ba]
__global__ void biasprep(const float* __restrict__ bin,
                         const float* __restrict__ bo,
                         const float* __restrict__ ba,
                         float* __restrict__ bqk, float* __restrict__ bfu) {
  const int i = threadIdx.x;
  if (i < 512) bqk[i] = (i < 256) ? bin[i] * 0.17677669529663687f : bin[i];
  if (i < 384) bfu[i] = (i < 256) ? bo[i] : ba[i - 256];
}

// ---------------------------------------------------------------------------
// B-resident MFMA GEMM, K=256 fixed. C[M,N] = A[M,256] @ W[N,256]^T + bias.
// BM=64, BN=128, 256 thr = 4 waves (2x2), wave tile 32x64.
// B panel (128 x 256 = 64KB bf16) staged ONCE per block in fragment order:
//   entry e = (step*8+cg)*64 + lane  -> 16B at Bs[e*8]; conflict-free reads.
// A: 2-slot LDS double buffer + depth-3 register prefetch; 1 barrier/step.
// ---------------------------------------------------------------------------
template <bool ABF, bool ADD2, bool RELU, bool OUTBF>
__global__ __launch_bounds__(256) void gemm_bres(
    const void* __restrict__ Ap, const float* __restrict__ A2,
    const unsigned short* __restrict__ Wbf, const float* __restrict__ bias,
    void* __restrict__ Cp, int M, int N) {
  __shared__ unsigned short Bs[32768];        // 64 KB
  __shared__ unsigned short As[2][64][40];    // 10 KB

  const float* Af = (const float*)Ap;
  const unsigned short* Ab = (const unsigned short*)Ap;
  float* Cf = (float*)Cp;
  unsigned short* Cb = (unsigned short*)Cp;

  const int t    = threadIdx.x;
  const int wave = t >> 6;
  const int l    = t & 63;
  const int n0   = blockIdx.x * 128;
  const int m0   = blockIdx.y * 64;
  const int wm   = (wave >> 1) * 32;
  const int wcg  = (wave & 1) * 4;   // col-group base (cg = wcg + fj)
  const int lr   = l & 15;
  const int lk8  = (l >> 4) * 8;

  // ---- stage B fragment-ordered ----
#pragma unroll
  for (int i = 0; i < 16; ++i) {
    const int e  = i * 256 + t;
    const int el = e & 63;
    const int cg = (e >> 6) & 7;
    const int st = e >> 9;
    const int row = n0 + cg * 16 + (el & 15);
    const int col = st * 32 + ((el >> 4) * 8);
    *reinterpret_cast<short8*>(&Bs[e * 8]) =
        *reinterpret_cast<const short8*>(&Wbf[(size_t)row * 256 + col]);
  }

  // ---- A prefetch machinery ----
  const int arow = t >> 2;
  const int acol = (t & 3) * 8;
  const int am   = m0 + arow;
  const bool aok = am < M;
  const size_t abase = (size_t)am * 256 + acol;

  float  fr[3][8];
  short8 br_[3];

  auto ALOAD = [&](int slot, int tt) {
    const int k0 = tt * 32;
    if constexpr (ABF) {
      br_[slot] = aok ? *reinterpret_cast<const short8*>(&Ab[abase + k0])
                      : (short8)(short)0;
    } else {
      if (aok) {
        const float4 a0 = *reinterpret_cast<const float4*>(&Af[abase + k0]);
        const float4 a1 = *reinterpret_cast<const float4*>(&Af[abase + k0 + 4]);
        fr[slot][0] = a0.x; fr[slot][1] = a0.y;
        fr[slot][2] = a0.z; fr[slot][3] = a0.w;
        fr[slot][4] = a1.x; fr[slot][5] = a1.y;
        fr[slot][6] = a1.z; fr[slot][7] = a1.w;
        if constexpr (ADD2) {
          const float4 b0 = *reinterpret_cast<const float4*>(&A2[abase + k0]);
          const float4 b1 = *reinterpret_cast<const float4*>(&A2[abase + k0 + 4]);
          fr[slot][0] += b0.x; fr[slot][1] += b0.y;
          fr[slot][2] += b0.z; fr[slot][3] += b0.w;
          fr[slot][4] += b1.x; fr[slot][5] += b1.y;
          fr[slot][6] += b1.z; fr[slot][7] += b1.w;
        }
      } else {
#pragma unroll
        for (int j = 0; j < 8; ++j) fr[slot][j] = 0.f;
      }
    }
  };
  auto AWRITE = [&](int slot, int tt) {
    if constexpr (ABF) {
      *reinterpret_cast<short8*>(&As[tt & 1][arow][acol]) = br_[slot];
    } else {
      alignas(16) unsigned short u[8];
#pragma unroll
      for (int j = 0; j < 8; ++j) u[j] = f2bf(fr[slot][j]);
      *reinterpret_cast<short8*>(&As[tt & 1][arow][acol]) =
          *reinterpret_cast<short8*>(&u[0]);
    }
  };

  f32x4 acc[2][4];
#pragma unroll
  for (int fi = 0; fi < 2; ++fi)
#pragma unroll
    for (int fj = 0; fj < 4; ++fj) acc[fi][fj] = (f32x4)0.f;

  ALOAD(0, 0); ALOAD(1, 1); ALOAD(2, 2);

#pragma unroll
  for (int tt = 0; tt < 8; ++tt) {
    AWRITE(tt % 3, tt);
    if (tt + 3 < 8) ALOAD(tt % 3, tt + 3);
    __syncthreads();

    short8 afr[2];
#pragma unroll
    for (int fi = 0; fi < 2; ++fi)
      afr[fi] = *reinterpret_cast<const short8*>(&As[tt & 1][wm + fi * 16 + lr][lk8]);

#pragma unroll
    for (int fj = 0; fj < 4; ++fj) {
      const short8 bfr = *reinterpret_cast<const short8*>(
          &Bs[(((tt * 8) + wcg + fj) * 64 + l) * 8]);
      acc[0][fj] = __builtin_amdgcn_mfma_f32_16x16x32_bf16(afr[0], bfr, acc[0][fj], 0, 0, 0);
      acc[1][fj] = __builtin_amdgcn_mfma_f32_16x16x32_bf16(afr[1], bfr, acc[1][fj], 0, 0, 0);
    }
  }

  // ---- epilogue ----
  const int or4 = (l >> 4) * 4;
#pragma unroll
  for (int fi = 0; fi < 2; ++fi) {
#pragma unroll
    for (int fj = 0; fj < 4; ++fj) {
      const int n = n0 + (wave & 1) * 64 + fj * 16 + lr;
      const float bn = bias[n];
#pragma unroll
      for (int i = 0; i < 4; ++i) {
        const int m = m0 + wm + fi * 16 + or4 + i;
        if (m < M) {
          float vv = acc[fi][fj][i] + bn;
          if (RELU) vv = fmaxf(vv, 0.f);
          if (OUTBF)
            Cb[(size_t)m * N + n] = f2bf(vv);
          else
            Cf[(size_t)m * N + n] = vv;
        }
      }
    }
  }
}

// ---------------------------------------------------------------------------
// Double-buffered MFMA bf16 GEMM (generic K) — used for ffn2 (K=1024).
// ---------------------------------------------------------------------------
template <bool ABF, bool ADD2, bool RELU, bool OUTBF>
__global__ __launch_bounds__(256) void gemm_db(
    const void* __restrict__ Ap, const float* __restrict__ A2,
    const unsigned short* __restrict__ Wbf, const float* __restrict__ bias,
    void* __restrict__ Cp, int M, int N, int K) {
  constexpr int LDR = 40;
  __shared__ unsigned short As[2][128][LDR];
  __shared__ unsigned short Bs[2][128][LDR];

  const float* Af = (const float*)Ap;
  const unsigned short* Ab = (const unsigned short*)Ap;
  float* Cf = (float*)Cp;
  unsigned short* Cb = (unsigned short*)Cp;

  const int t    = threadIdx.x;
  const int wave = t >> 6;
  const int l    = t & 63;
  const int n0   = blockIdx.x * 128;
  const int m0   = blockIdx.y * 128;
  const int wm   = (wave >> 1) * 64;
  const int wn   = (wave & 1) * 64;
  const int srow = t >> 1;
  const int sseg = (t & 1) * 16;
  const int lr   = l & 15;
  const int lk   = (l >> 4) * 8;

  const int am = m0 + srow;
  const bool aok = am < M;
  const size_t arow = (size_t)am * K;
  const size_t brow = (size_t)(n0 + srow) * K;

  f32x4 acc[4][4];
#pragma unroll
  for (int i = 0; i < 4; ++i)
#pragma unroll
    for (int j = 0; j < 4; ++j) acc[i][j] = (f32x4)0.f;

  short8 ar0, ar1, br0, br1;

  auto LOAD = [&](int k0) {
    if constexpr (ABF) {
      if (aok) {
        ar0 = *reinterpret_cast<const short8*>(&Ab[arow + k0 + sseg]);
        ar1 = *reinterpret_cast<const short8*>(&Ab[arow + k0 + sseg + 8]);
      } else {
        ar0 = (short8)(short)0; ar1 = (short8)(short)0;
      }
    } else {
      if (aok) {
        float f[16];
#pragma unroll
        for (int j = 0; j < 4; ++j) {
          const float4 av =
              *reinterpret_cast<const float4*>(&Af[arow + k0 + sseg + 4 * j]);
          f[4 * j + 0] = av.x; f[4 * j + 1] = av.y;
          f[4 * j + 2] = av.z; f[4 * j + 3] = av.w;
        }
        if constexpr (ADD2) {
#pragma unroll
          for (int j = 0; j < 4; ++j) {
            const float4 av =
                *reinterpret_cast<const float4*>(&A2[arow + k0 + sseg + 4 * j]);
            f[4 * j + 0] += av.x; f[4 * j + 1] += av.y;
            f[4 * j + 2] += av.z; f[4 * j + 3] += av.w;
          }
        }
        alignas(16) unsigned short u[16];
#pragma unroll
        for (int j = 0; j < 16; ++j) u[j] = f2bf(f[j]);
        ar0 = *reinterpret_cast<short8*>(&u[0]);
        ar1 = *reinterpret_cast<short8*>(&u[8]);
      } else {
        ar0 = (short8)(short)0; ar1 = (short8)(short)0;
      }
    }
    br0 = *reinterpret_cast<const short8*>(&Wbf[brow + k0 + sseg]);
    br1 = *reinterpret_cast<const short8*>(&Wbf[brow + k0 + sseg + 8]);
  };

  const int nt = K >> 5;
  LOAD(0);
  for (int tt = 0; tt < nt; ++tt) {
    const int cur = tt & 1;
    *reinterpret_cast<short8*>(&As[cur][srow][sseg])     = ar0;
    *reinterpret_cast<short8*>(&As[cur][srow][sseg + 8]) = ar1;
    *reinterpret_cast<short8*>(&Bs[cur][srow][sseg])     = br0;
    *reinterpret_cast<short8*>(&Bs[cur][srow][sseg + 8]) = br1;
    if (tt + 1 < nt) LOAD((tt + 1) << 5);
    __syncthreads();

    short8 af[4], bfr[4];
#pragma unroll
    for (int fi = 0; fi < 4; ++fi)
      af[fi] = *reinterpret_cast<const short8*>(&As[cur][wm + fi * 16 + lr][lk]);
#pragma unroll
    for (int fj = 0; fj < 4; ++fj)
      bfr[fj] = *reinterpret_cast<const short8*>(&Bs[cur][wn + fj * 16 + lr][lk]);

#pragma unroll
    for (int fi = 0; fi < 4; ++fi)
#pragma unroll
      for (int fj = 0; fj < 4; ++fj)
        acc[fi][fj] = __builtin_amdgcn_mfma_f32_16x16x32_bf16(
            af[fi], bfr[fj], acc[fi][fj], 0, 0, 0);
  }

  const int orow = (l >> 4) * 4;
#pragma unroll
  for (int fi = 0; fi < 4; ++fi) {
#pragma unroll
    for (int fj = 0; fj < 4; ++fj) {
      const int n = n0 + wn + fj * 16 + lr;
      const float bn = bias[n];
#pragma unroll
      for (int i = 0; i < 4; ++i) {
        const int m = m0 + wm + fi * 16 + orow + i;
        if (m < M) {
          float vv = acc[fi][fj][i] + bn;
          if (RELU) vv = fmaxf(vv, 0.f);
          if (OUTBF)
            Cb[(size_t)m * N + n] = f2bf(vv);
          else
            Cf[(size_t)m * N + n] = vv;
        }
      }
    }
  }
}

// ---------------------------------------------------------------------------
// Deformable sampling. One block (256 thr) per (b,q). tid = h*32 + d.
// ---------------------------------------------------------------------------
__global__ __launch_bounds__(256) void deform(const float* __restrict__ refp,
                                              const float* __restrict__ offlog,
                                              const unsigned short* __restrict__ v,
                                              float* __restrict__ acc) {
  __shared__ float aw[H_ * L_ * P_];
  const int bq = blockIdx.x;
  const int b  = bq / NQ_;
  const int t  = threadIdx.x;
  const int h  = t >> 5, d = t & 31;

  if (t < 128) aw[t] = offlog[(size_t)bq * 384 + 256 + t];
  __syncthreads();
  if (t < 8) {
    float mx = -1e30f;
#pragma unroll
    for (int i = 0; i < 16; ++i) mx = fmaxf(mx, aw[t * 16 + i]);
    float e[16], s = 0.f;
#pragma unroll
    for (int i = 0; i < 16; ++i) { e[i] = expf(aw[t * 16 + i] - mx); s += e[i]; }
    const float inv = 1.f / s;
#pragma unroll
    for (int i = 0; i < 16; ++i) aw[t * 16 + i] = e[i] * inv;
  }
  __syncthreads();

  constexpr int ST[4] = {0, 16000, 20000, 21000};
  constexpr int HL[4] = {100, 50, 25, 13};
  constexpr int WL[4] = {160, 80, 40, 20};

  float a = 0.f;
#pragma unroll
  for (int l = 0; l < L_; ++l) {
    const float rx = refp[(bq * L_ + l) * 2 + 0];
    const float ry = refp[(bq * L_ + l) * 2 + 1];
    const float Wf = (float)WL[l], Hf = (float)HL[l];
    const int   Wi = WL[l], Hi = HL[l];
    const int vbase = (b * NV_ + ST[l]) * D_ + h * DH + d;
#pragma unroll
    for (int p = 0; p < P_; ++p) {
      const float ox = offlog[(size_t)bq * 384 + h * 32 + l * 8 + p * 2 + 0];
      const float oy = offlog[(size_t)bq * 384 + h * 32 + l * 8 + p * 2 + 1];
      const float locx = rx + ox / Wf;
      const float locy = ry + oy / Hf;
      const float xl = locx * Wf - 0.5f;
      const float yl = locy * Hf - 0.5f;
      const float x0 = floorf(xl), y0 = floorf(yl);
      const float wx = xl - x0, wy = yl - y0;
      const int x0i = (int)x0, y0i = (int)y0;
      const float w = aw[h * 16 + l * 4 + p];

      float s = 0.f;
#pragma unroll
      for (int c = 0; c < 4; ++c) {
        const int xi = x0i + (c & 1);
        const int yi = y0i + (c >> 1);
        const float cw = ((c & 1) ? wx : 1.f - wx) * ((c >> 1) ? wy : 1.f - wy);
        const bool valid = (xi >= 0) && (xi < Wi) && (yi >= 0) && (yi < Hi);
        const int xc = min(max(xi, 0), Wi - 1);
        const int yc = min(max(yi, 0), Hi - 1);
        const float g = bf2f(v[vbase + (yc * Wi + xc) * D_]);
        s += valid ? g * cw : 0.f;
      }
      a += w * s;
    }
  }
  acc[bq * D_ + t] = a;
}

// ---------------------------------------------------------------------------
// MFMA flash MHA (bf16 inputs; QK-scale pre-folded into Q projection).
// ---------------------------------------------------------------------------
constexpr int TQM  = 64;
constexpr int NQTM = (NQ_ + TQM - 1) / TQM;   // 15

__global__ __launch_bounds__(256) void mha_mfma(
    const unsigned short* __restrict__ qkh,
    const unsigned short* __restrict__ vh,
    unsigned short* __restrict__ o) {
  __shared__ unsigned short Qs[64][40];
  __shared__ unsigned short Ks[64][40];
  __shared__ unsigned short Vts[32][72];
  __shared__ unsigned short Ps[64][72];

  const int bx = blockIdx.x;
  const int qt = bx % NQTM;
  const int h  = (bx / NQTM) % H_;
  const int b  = bx / (NQTM * H_);
  const int t  = threadIdx.x;
  const int wave = t >> 6;
  const int l    = t & 63;
  const int q0   = qt * TQM;
  const int wrow = wave * 16;
  const int lr   = l & 15;
  const int lkb  = (l >> 4) * 8;

  {
    const int r = t >> 2, cb = (t & 3) * 8;
    short8 u;
    if (q0 + r < NQ_)
      u = *reinterpret_cast<const short8*>(
          &qkh[(size_t)(b * NQ_ + q0 + r) * 512 + h * DH + cb]);
    else
      u = (short8)(short)0;
    *reinterpret_cast<short8*>(&Qs[r][cb]) = u;
  }
  __syncthreads();

  const short8 qa = *reinterpret_cast<const short8*>(&Qs[wrow + lr][lkb]);

  f32x4 oacc[2];
  oacc[0] = (f32x4)0.f; oacc[1] = (f32x4)0.f;
  float m_[4] = {-1e30f, -1e30f, -1e30f, -1e30f};
  float l_[4] = {0.f, 0.f, 0.f, 0.f};

  for (int kt = 0; kt < NQTM; ++kt) {
    const int k0 = kt * 64;
    const int nk = min(64, NQ_ - k0);
    __syncthreads();

    {
      const int r = t >> 2, cb = (t & 3) * 8;
      short8 u;
      if (r < nk)
        u = *reinterpret_cast<const short8*>(
            &qkh[(size_t)(b * NQ_ + k0 + r) * 512 + 256 + h * DH + cb]);
      else
        u = (short8)(short)0;
      *reinterpret_cast<short8*>(&Ks[r][cb]) = u;
    }
    {
      const int k = t & 63, db = (t >> 6) * 8;
      short8 u;
      if (k < nk)
        u = *reinterpret_cast<const short8*>(
            &vh[(size_t)(b * NQ_ + k0 + k) * D_ + h * DH + db]);
      else
        u = (short8)(short)0;
#pragma unroll
      for (int j = 0; j < 8; ++j) Vts[db + j][k] = (unsigned short)u[j];
    }
    __syncthreads();

    f32x4 sacc[4];
#pragma unroll
    for (int fj = 0; fj < 4; ++fj)
      sacc[fj] = __builtin_amdgcn_mfma_f32_16x16x32_bf16(
          qa, *reinterpret_cast<const short8*>(&Ks[16 * fj + lr][lkb]),
          (f32x4)0.f, 0, 0, 0);

    bool cv[4];
#pragma unroll
    for (int fj = 0; fj < 4; ++fj) cv[fj] = (16 * fj + lr) < nk;

    float p0[4], p1[4], p2[4], p3[4], sc_[4];
#pragma unroll
    for (int i = 0; i < 4; ++i) {
      float tm = -1e30f;
      if (cv[0]) tm = fmaxf(tm, sacc[0][i]);
      if (cv[1]) tm = fmaxf(tm, sacc[1][i]);
      if (cv[2]) tm = fmaxf(tm, sacc[2][i]);
      if (cv[3]) tm = fmaxf(tm, sacc[3][i]);
      tm = fmaxf(tm, __shfl_xor(tm, 1));
      tm = fmaxf(tm, __shfl_xor(tm, 2));
      tm = fmaxf(tm, __shfl_xor(tm, 4));
      tm = fmaxf(tm, __shfl_xor(tm, 8));
      const float mn = fmaxf(m_[i], tm);
      sc_[i] = __expf(m_[i] - mn);
      m_[i] = mn;
      const float e0 = cv[0] ? __expf(sacc[0][i] - mn) : 0.f;
      const float e1 = cv[1] ? __expf(sacc[1][i] - mn) : 0.f;
      const float e2 = cv[2] ? __expf(sacc[2][i] - mn) : 0.f;
      const float e3 = cv[3] ? __expf(sacc[3][i] - mn) : 0.f;
      p0[i] = e0; p1[i] = e1; p2[i] = e2; p3[i] = e3;
      float rs = e0 + e1 + e2 + e3;
      rs += __shfl_xor(rs, 1);
      rs += __shfl_xor(rs, 2);
      rs += __shfl_xor(rs, 4);
      rs += __shfl_xor(rs, 8);
      l_[i] = l_[i] * sc_[i] + rs;
    }

#pragma unroll
    for (int i = 0; i < 4; ++i) {
      const int pr = wrow + (l >> 4) * 4 + i;
      Ps[pr][0  + lr] = f2bf(p0[i]);
      Ps[pr][16 + lr] = f2bf(p1[i]);
      Ps[pr][32 + lr] = f2bf(p2[i]);
      Ps[pr][48 + lr] = f2bf(p3[i]);
    }
    __syncthreads();

    const short8 pa0 = *reinterpret_cast<const short8*>(&Ps[wrow + lr][lkb]);
    const short8 pa1 = *reinterpret_cast<const short8*>(&Ps[wrow + lr][lkb + 32]);
#pragma unroll
    for (int nt = 0; nt < 2; ++nt) {
      f32x4 c = oacc[nt];
#pragma unroll
      for (int i = 0; i < 4; ++i) c[i] *= sc_[i];
      c = __builtin_amdgcn_mfma_f32_16x16x32_bf16(
          pa0, *reinterpret_cast<const short8*>(&Vts[16 * nt + lr][lkb]), c, 0, 0, 0);
      c = __builtin_amdgcn_mfma_f32_16x16x32_bf16(
          pa1, *reinterpret_cast<const short8*>(&Vts[16 * nt + lr][lkb + 32]), c, 0, 0, 0);
      oacc[nt] = c;
    }
  }

#pragma unroll
  for (int i = 0; i < 4; ++i) {
    const int r = (l >> 4) * 4 + i;
    const int q = q0 + wrow + r;
    if (q < NQ_) {
      const float inv = 1.f / l_[i];
      o[(size_t)(b * NQ_ + q) * D_ + h * DH + 0  + lr] = f2bf(oacc[0][i] * inv);
      o[(size_t)(b * NQ_ + q) * D_ + h * DH + 16 + lr] = f2bf(oacc[1][i] * inv);
    }
  }
}

// ---------------------------------------------------------------------------
// out = LayerNorm(res + add) * g + b
// ---------------------------------------------------------------------------
__global__ __launch_bounds__(256) void ln(const float* __restrict__ res,
                                          const float* __restrict__ add,
                                          const float* __restrict__ g,
                                          const float* __restrict__ bt,
                                          float* __restrict__ out) {
  __shared__ float red[256];
  const int r = blockIdx.x, t = threadIdx.x;
  const float x = res[r * D_ + t] + add[r * D_ + t];
  red[t] = x;
  __syncthreads();
  for (int s = 128; s > 0; s >>= 1) {
    if (t < s) red[t] += red[t + s];
    __syncthreads();
  }
  const float mean = red[0] * (1.f / D_);
  __syncthreads();
  const float dx = x - mean;
  red[t] = dx * dx;
  __syncthreads();
  for (int s = 128; s > 0; s >>= 1) {
    if (t < s) red[t] += red[t + s];
    __syncthreads();
  }
  const float var = red[0] * (1.f / D_);
  out[r * D_ + t] = dx * rsqrtf(var + 1e-5f) * g[t] + bt[t];
}

// ---------------------------------------------------------------------------
extern "C" void kernel_launch(void* const* d_in, const int* in_sizes, int n_in,
                              void* d_out, int out_size, void* d_ws,
                              size_t ws_size, hipStream_t stream) {
  const float* tgt   = (const float*)d_in[0];
  const float* pos   = (const float*)d_in[1];
  const float* refp  = (const float*)d_in[2];
  const float* mem   = (const float*)d_in[3];
  const float* Wv    = (const float*)d_in[4];
  const float* bv    = (const float*)d_in[5];
  const float* Wo    = (const float*)d_in[6];
  const float* bo    = (const float*)d_in[7];
  const float* Wa    = (const float*)d_in[8];
  const float* ba    = (const float*)d_in[9];
  const float* Wca   = (const float*)d_in[10];
  const float* bca   = (const float*)d_in[11];
  const float* g1    = (const float*)d_in[12];
  const float* b1    = (const float*)d_in[13];
  const float* Win   = (const float*)d_in[14];
  const float* bin   = (const float*)d_in[15];
  const float* Wsa   = (const float*)d_in[16];
  const float* bsa   = (const float*)d_in[17];
  const float* g2    = (const float*)d_in[18];
  const float* b2    = (const float*)d_in[19];
  const float* W1    = (const float*)d_in[20];
  const float* bb1   = (const float*)d_in[21];
  const float* W2    = (const float*)d_in[22];
  const float* bb2   = (const float*)d_in[23];
  const float* g3    = (const float*)d_in[24];
  const float* b3    = (const float*)d_in[25];

  char* cur = (char*)d_ws;
  auto alloc = [&](size_t bytes) {
    char* p = cur;
    cur += (bytes + 255) & ~(size_t)255;
    return (void*)p;
  };
  unsigned short* v_bf    = (unsigned short*)alloc((size_t)MV * 256 * 2);
  float*          offlog  = (float*)alloc((size_t)MQ * 384 * 4);
  float*          accb    = (float*)alloc((size_t)MQ * 256 * 4);
  float*          tmp     = (float*)alloc((size_t)MQ * 256 * 4);
  float*          x1      = (float*)alloc((size_t)MQ * 256 * 4);
  float*          x2      = (float*)alloc((size_t)MQ * 256 * 4);
  unsigned short* qkh_bf  = (unsigned short*)alloc((size_t)MQ * 512 * 2);
  unsigned short* vh_bf   = (unsigned short*)alloc((size_t)MQ * 256 * 2);
  unsigned short* obuf_bf = (unsigned short*)alloc((size_t)MQ * 256 * 2);
  unsigned short* h1_bf   = (unsigned short*)alloc((size_t)MQ * 1024 * 2);
  unsigned short* Wv_bf   = (unsigned short*)alloc(65536 * 2);
  unsigned short* Wfu_bf  = (unsigned short*)alloc(98304 * 2);   // [Wo|Wa]
  unsigned short* Wca_bf  = (unsigned short*)alloc(65536 * 2);
  unsigned short* Win_bf  = (unsigned short*)alloc(196608 * 2);
  unsigned short* Wsa_bf  = (unsigned short*)alloc(65536 * 2);
  unsigned short* W1_bf   = (unsigned short*)alloc(262144 * 2);
  unsigned short* W2_bf   = (unsigned short*)alloc(262144 * 2);
  float*          biasqk  = (float*)alloc(512 * 4);
  float*          bfused  = (float*)alloc(384 * 4);

  const float qscale = 0.17677669529663687f;  // 1/sqrt(32)

  CvtArgs ca;
  ca.src[0] = Wv;            ca.dst[0] = Wv_bf;          ca.n[0] = 65536;  ca.scl[0] = 1.f;
  ca.src[1] = Wo;            ca.dst[1] = Wfu_bf;         ca.n[1] = 65536;  ca.scl[1] = 1.f;
  ca.src[2] = Wa;            ca.dst[2] = Wfu_bf + 65536; ca.n[2] = 32768;  ca.scl[2] = 1.f;
  ca.src[3] = Wca;           ca.dst[3] = Wca_bf;         ca.n[3] = 65536;  ca.scl[3] = 1.f;
  ca.src[4] = Win;           ca.dst[4] = Win_bf;         ca.n[4] = 65536;  ca.scl[4] = qscale;
  ca.src[5] = Win + 65536;   ca.dst[5] = Win_bf + 65536; ca.n[5] = 131072; ca.scl[5] = 1.f;
  ca.src[6] = Wsa;           ca.dst[6] = Wsa_bf;         ca.n[6] = 65536;  ca.scl[6] = 1.f;
  ca.src[7] = W1;            ca.dst[7] = W1_bf;          ca.n[7] = 262144; ca.scl[7] = 1.f;
  ca.src[8] = W2;            ca.dst[8] = W2_bf;          ca.n[8] = 262144; ca.scl[8] = 1.f;
  cvtw<<<dim3(64, 9), 256, 0, stream>>>(ca);
  biasprep<<<1, 512, 0, stream>>>(bin, bo, ba, biasqk, bfused);

  const int mqb64 = (MQ + 63) / 64;   // 57
  const int mvb64 = (MV + 63) / 64;   // 1329

  // value projection -> bf16
  gemm_bres<false, false, false, true><<<dim3(2, mvb64), 256, 0, stream>>>(
      mem, nullptr, Wv_bf, bv, v_bf, MV, 256);
  // (tgt+pos) @ [Wo|Wa] -> offlog f32
  gemm_bres<false, true, false, false><<<dim3(3, mqb64), 256, 0, stream>>>(
      tgt, pos, Wfu_bf, bfused, offlog, MQ, 384);
  deform<<<MQ, 256, 0, stream>>>(refp, offlog, v_bf, accb);
  gemm_bres<false, false, false, false><<<dim3(2, mqb64), 256, 0, stream>>>(
      accb, nullptr, Wca_bf, bca, tmp, MQ, 256);
  ln<<<MQ, 256, 0, stream>>>(tgt, tmp, g1, b1, x1);
  // (x1+pos) @ Win[QK] -> qkh bf16 (Q pre-scaled)
  gemm_bres<false, true, false, true><<<dim3(4, mqb64), 256, 0, stream>>>(
      x1, pos, Win_bf, biasqk, qkh_bf, MQ, 512);
  // x1 @ Win[V] -> vh bf16
  gemm_bres<false, false, false, true><<<dim3(2, mqb64), 256, 0, stream>>>(
      x1, nullptr, Win_bf + 512 * 256, bin + 512, vh_bf, MQ, 256);
  mha_mfma<<<B_ * H_ * NQTM, 256, 0, stream>>>(qkh_bf, vh_bf, obuf_bf);
  gemm_bres<true, false, false, false><<<dim3(2, mqb64), 256, 0, stream>>>(
      obuf_bf, nullptr, Wsa_bf, bsa, tmp, MQ, 256);
  ln<<<MQ, 256, 0, stream>>>(x1, tmp, g2, b2, x2);
  gemm_bres<false, false, true, true><<<dim3(8, mqb64), 256, 0, stream>>>(
      x2, nullptr, W1_bf, bb1, h1_bf, MQ, 1024);
  gemm_db<true, false, false, false><<<dim3(2, (MQ + 127) / 128), 256, 0, stream>>>(
      h1_bf, nullptr, W2_bf, bb2, tmp, MQ, 256, 1024);
  ln<<<MQ, 256, 0, stream>>>(x2, tmp, g3, b3, (float*)d_out);
}